// Round 1
// baseline (1283.240 us; speedup 1.0000x reference)
//
#include <hip/hip_runtime.h>
#include <math.h>

#define BM 128
#define BN 128
#define BK 16

// C[M,N] = op: A[M,K] row-major times (TRANS_B ? B[N,K]^T : B[K,N]), optional
// scale and bias. All dims assumed multiples of tile sizes (true here:
// 1024/4096).
template <bool TRANS_B, bool BIAS, bool SCALE>
__global__ __launch_bounds__(256) void gemm_f32(
    const float* __restrict__ A, const float* __restrict__ B,
    const float* __restrict__ bias, float* __restrict__ C, int M, int N, int K,
    float scale) {
  __shared__ float As[BK][BM + 4];
  __shared__ float Bs[BK][BN + 4];
  const int tid = threadIdx.x;
  const int bm = blockIdx.y * BM;
  const int bn = blockIdx.x * BN;
  const int tx = tid & 15;   // 0..15 -> 8 cols each
  const int ty = tid >> 4;   // 0..15 -> 8 rows each
  float acc[8][8] = {};

  for (int k0 = 0; k0 < K; k0 += BK) {
    // ---- stage A tile: rows bm..bm+127, cols k0..k0+15 (transpose into LDS)
    {
      const int r = tid >> 2;          // 0..63
      const int c = (tid & 3) * 4;     // 0,4,8,12
#pragma unroll
      for (int i = 0; i < 2; ++i) {
        const int row = r + i * 64;
        const float4 v = *reinterpret_cast<const float4*>(
            &A[(size_t)(bm + row) * K + k0 + c]);
        As[c + 0][row] = v.x;
        As[c + 1][row] = v.y;
        As[c + 2][row] = v.z;
        As[c + 3][row] = v.w;
      }
    }
    // ---- stage B tile
    if (!TRANS_B) {
      // B[K,N]: rows k0..k0+15, cols bn..bn+127 (copy straight)
      const int r = tid >> 5;          // 0..7
      const int c = (tid & 31) * 4;    // 0..124
#pragma unroll
      for (int i = 0; i < 2; ++i) {
        const int row = r + i * 8;
        const float4 v = *reinterpret_cast<const float4*>(
            &B[(size_t)(k0 + row) * N + bn + c]);
        *reinterpret_cast<float4*>(&Bs[row][c]) = v;
      }
    } else {
      // B[N,K]: rows bn..bn+127, cols k0..k0+15 (transpose into LDS)
      const int r = tid >> 2;
      const int c = (tid & 3) * 4;
#pragma unroll
      for (int i = 0; i < 2; ++i) {
        const int row = r + i * 64;
        const float4 v = *reinterpret_cast<const float4*>(
            &B[(size_t)(bn + row) * K + k0 + c]);
        Bs[c + 0][row] = v.x;
        Bs[c + 1][row] = v.y;
        Bs[c + 2][row] = v.z;
        Bs[c + 3][row] = v.w;
      }
    }
    __syncthreads();

#pragma unroll
    for (int k = 0; k < BK; ++k) {
      float a[8], b[8];
      *reinterpret_cast<float4*>(&a[0]) =
          *reinterpret_cast<const float4*>(&As[k][ty * 8]);
      *reinterpret_cast<float4*>(&a[4]) =
          *reinterpret_cast<const float4*>(&As[k][ty * 8 + 4]);
      *reinterpret_cast<float4*>(&b[0]) =
          *reinterpret_cast<const float4*>(&Bs[k][tx * 8]);
      *reinterpret_cast<float4*>(&b[4]) =
          *reinterpret_cast<const float4*>(&Bs[k][tx * 8 + 4]);
#pragma unroll
      for (int i = 0; i < 8; ++i)
#pragma unroll
        for (int j = 0; j < 8; ++j) acc[i][j] = fmaf(a[i], b[j], acc[i][j]);
    }
    __syncthreads();
  }

  // ---- epilogue
#pragma unroll
  for (int i = 0; i < 8; ++i) {
    const int row = bm + ty * 8 + i;
#pragma unroll
    for (int j = 0; j < 8; j += 4) {
      const int col = bn + tx * 8 + j;
      float4 v;
      v.x = acc[i][j + 0];
      v.y = acc[i][j + 1];
      v.z = acc[i][j + 2];
      v.w = acc[i][j + 3];
      if (SCALE) {
        v.x *= scale; v.y *= scale; v.z *= scale; v.w *= scale;
      }
      if (BIAS) {
        v.x += bias[col + 0]; v.y += bias[col + 1];
        v.z += bias[col + 2]; v.w += bias[col + 3];
      }
      *reinterpret_cast<float4*>(&C[(size_t)row * N + col]) = v;
    }
  }
}

// In-place row softmax; one block per row, N multiple of 1024.
__global__ __launch_bounds__(256) void softmax_rows(float* __restrict__ S,
                                                    int N) {
  const int row = blockIdx.x;
  float* p = S + (size_t)row * N;
  const int tid = threadIdx.x;
  __shared__ float red[8];

  // pass 1: max
  float m = -INFINITY;
  for (int i = tid * 4; i < N; i += 1024) {
    const float4 v = *reinterpret_cast<const float4*>(&p[i]);
    m = fmaxf(fmaxf(fmaxf(v.x, v.y), fmaxf(v.z, v.w)), m);
  }
#pragma unroll
  for (int off = 32; off > 0; off >>= 1) m = fmaxf(m, __shfl_xor(m, off));
  if ((tid & 63) == 0) red[tid >> 6] = m;
  __syncthreads();
  m = fmaxf(fmaxf(red[0], red[1]), fmaxf(red[2], red[3]));

  // pass 2: sum of exp
  float s = 0.f;
  for (int i = tid * 4; i < N; i += 1024) {
    const float4 v = *reinterpret_cast<const float4*>(&p[i]);
    s += expf(v.x - m) + expf(v.y - m) + expf(v.z - m) + expf(v.w - m);
  }
#pragma unroll
  for (int off = 32; off > 0; off >>= 1) s += __shfl_xor(s, off);
  if ((tid & 63) == 0) red[4 + (tid >> 6)] = s;
  __syncthreads();
  s = red[4] + red[5] + red[6] + red[7];
  const float inv = 1.0f / s;

  // pass 3: write normalized
  for (int i = tid * 4; i < N; i += 1024) {
    float4 v = *reinterpret_cast<const float4*>(&p[i]);
    v.x = expf(v.x - m) * inv;
    v.y = expf(v.y - m) * inv;
    v.z = expf(v.z - m) * inv;
    v.w = expf(v.w - m) * inv;
    *reinterpret_cast<float4*>(&p[i]) = v;
  }
}

extern "C" void kernel_launch(void* const* d_in, const int* in_sizes, int n_in,
                              void* d_out, int out_size, void* d_ws,
                              size_t ws_size, hipStream_t stream) {
  const float* X = (const float*)d_in[0];     // [B, D]
  const float* R = (const float*)d_in[1];     // [D, D]
  const float* W = (const float*)d_in[2];     // [D, D] (out, in)
  const float* bv = (const float*)d_in[3];    // [D]
  float* out = (float*)d_out;                 // [B, D]

  const int B = 4096, D = 1024;
  const float scale = 0.03125f;  // 1/sqrt(1024)

  // workspace layout (floats): M[D*D] | T[B*D] | S[B*B] | A[B*D]  = 100 MB
  float* Mw = (float*)d_ws;
  float* T = Mw + (size_t)D * D;
  float* S = T + (size_t)B * D;
  float* Aw = S + (size_t)B * B;

  const dim3 blk(256);

  // M = R @ R   [D,D]
  gemm_f32<false, false, false>
      <<<dim3(D / BN, D / BM), blk, 0, stream>>>(R, R, nullptr, Mw, D, D, D, 1.f);
  // T = X @ M   [B,D]
  gemm_f32<false, false, false>
      <<<dim3(D / BN, B / BM), blk, 0, stream>>>(X, Mw, nullptr, T, B, D, D, 1.f);
  // S = scale * (T @ X^T)   [B,B]
  gemm_f32<true, false, true>
      <<<dim3(B / BN, B / BM), blk, 0, stream>>>(T, X, nullptr, S, B, B, D, scale);
  // softmax rows of S in place
  softmax_rows<<<dim3(B), blk, 0, stream>>>(S, B);
  // A = S @ X   [B,D]
  gemm_f32<false, false, false>
      <<<dim3(D / BN, B / BM), blk, 0, stream>>>(S, X, nullptr, Aw, B, D, B, 1.f);
  // out = A @ W^T + b   [B,D]
  gemm_f32<true, true, false>
      <<<dim3(D / BN, B / BM), blk, 0, stream>>>(Aw, W, bv, out, B, D, D, 1.f);
}

// Round 2
// 427.494 us; speedup vs baseline: 3.0018x; 3.0018x over previous
//
#include <hip/hip_runtime.h>
#include <math.h>
#include <stdint.h>

using f16 = _Float16;
using half8 = __attribute__((ext_vector_type(8))) f16;
using half4 = __attribute__((ext_vector_type(4))) f16;
using f32x4 = __attribute__((ext_vector_type(4))) float;

__device__ __forceinline__ void gl_lds16(const f16* g, f16* l) {
  __builtin_amdgcn_global_load_lds(
      (const __attribute__((address_space(1))) void*)g,
      (__attribute__((address_space(3))) void*)l, 16, 0, 0);
}

// C[M,N] = scale * sum_pairs Aplane_i[M,K] . Bplane_j[N,K]^T  (+bias)
// NP = planes per operand (1 -> 1 product, 2 -> hh+hm+mh).
// EPI: 0 = fp32 out (scale, opt bias), 1 = split2 fp16 planes, 2 = fp16 plane.
template <int NP, int EPI, bool BIASF>
__global__ __launch_bounds__(256, 2) void gemm_mp(
    const f16* __restrict__ Ap, const f16* __restrict__ Bp,
    void* __restrict__ Cv, const float* __restrict__ bias, int M, int N, int K,
    long sAp, long sBp, long sCp, float scale) {
  __shared__ f16 As[NP * 128 * 32];
  __shared__ f16 Bs[NP * 128 * 32];
  const int tid = threadIdx.x;
  const int lane = tid & 63;
  const int wave = tid >> 6;
  const int wr = (wave >> 1) * 64;
  const int wc = (wave & 1) * 64;
  const int bm = blockIdx.y * 128;
  const int bn = blockIdx.x * 128;

  // fragment LDS offsets (half-elements), XOR-swizzled granules
  int aoff[NP][4], boff[NP][4];
#pragma unroll
  for (int p = 0; p < NP; ++p) {
#pragma unroll
    for (int m = 0; m < 4; ++m) {
      const int row = wr + m * 16 + (lane & 15);
      const int kga = (lane >> 4) ^ ((row >> 1) & 3);
      aoff[p][m] = (p * 512 + row * 4 + kga) * 8;
      const int col = wc + m * 16 + (lane & 15);
      const int kgb = (lane >> 4) ^ ((col >> 1) & 3);
      boff[p][m] = (p * 512 + col * 4 + kgb) * 8;
    }
  }

  f32x4 acc[4][4];
#pragma unroll
  for (int m = 0; m < 4; ++m)
#pragma unroll
    for (int n = 0; n < 4; ++n) acc[m][n] = (f32x4){0.f, 0.f, 0.f, 0.f};

  for (int k0 = 0; k0 < K; k0 += 32) {
    // ---- stage A+B tiles via global_load_lds (16B/lane), swizzled source
#pragma unroll
    for (int i = 0; i < NP * 4; ++i) {
      const int g0 = i * 256 + wave * 64;  // wave-uniform granule base
      const bool isB = g0 >= NP * 512;
      const int ga0 = g0 - (isB ? NP * 512 : 0);
      const int ga = ga0 + lane;
      const int pl = ga >> 9;
      const int r = (ga >> 2) & 127;
      const int cg = (ga & 3) ^ ((r >> 1) & 3);
      const f16* gs = (isB ? Bp + (size_t)pl * sBp + (size_t)(bn + r) * K
                           : Ap + (size_t)pl * sAp + (size_t)(bm + r) * K) +
                      k0 + cg * 8;
      f16* ld = (isB ? Bs : As) + (size_t)ga0 * 8;
      gl_lds16(gs, ld);
    }
    __syncthreads();

    half8 af[NP][4], bf[NP][4];
#pragma unroll
    for (int p = 0; p < NP; ++p) {
#pragma unroll
      for (int m = 0; m < 4; ++m) {
        af[p][m] = *(const half8*)&As[aoff[p][m]];
        bf[p][m] = *(const half8*)&Bs[boff[p][m]];
      }
    }
#pragma unroll
    for (int m = 0; m < 4; ++m) {
#pragma unroll
      for (int n = 0; n < 4; ++n) {
        acc[m][n] = __builtin_amdgcn_mfma_f32_16x16x32_f16(af[0][m], bf[0][n],
                                                           acc[m][n], 0, 0, 0);
        if (NP == 2) {
          acc[m][n] = __builtin_amdgcn_mfma_f32_16x16x32_f16(
              af[0][m], bf[1][n], acc[m][n], 0, 0, 0);
          acc[m][n] = __builtin_amdgcn_mfma_f32_16x16x32_f16(
              af[1][m], bf[0][n], acc[m][n], 0, 0, 0);
        }
      }
    }
    __syncthreads();
  }

  // ---- epilogue. C/D layout: col = lane&15, row = (lane>>4)*4 + q
#pragma unroll
  for (int m = 0; m < 4; ++m) {
#pragma unroll
    for (int n = 0; n < 4; ++n) {
      const int col = bn + wc + n * 16 + (lane & 15);
#pragma unroll
      for (int q = 0; q < 4; ++q) {
        const int row = bm + wr + m * 16 + (lane >> 4) * 4 + q;
        float v = acc[m][n][q] * scale;
        if (EPI == 0) {
          if (BIASF) v += bias[col];
          ((float*)Cv)[(size_t)row * N + col] = v;
        } else if (EPI == 1) {
          f16* C = (f16*)Cv;
          const f16 h = (f16)v;
          C[(size_t)row * N + col] = h;
          C[sCp + (size_t)row * N + col] = (f16)(v - (float)h);
        } else {
          ((f16*)Cv)[(size_t)row * N + col] = (f16)v;
        }
      }
    }
  }
}

// fp32 -> NP fp16 planes (elementwise), one float4 per thread
template <int NP>
__global__ __launch_bounds__(256) void split_n(const float* __restrict__ in,
                                               f16* __restrict__ out,
                                               long planeStride, int n4) {
  const int i = blockIdx.x * 256 + threadIdx.x;
  if (i >= n4) return;
  const float4 v = ((const float4*)in)[i];
  const float vv[4] = {v.x, v.y, v.z, v.w};
  half4 h, mm;
#pragma unroll
  for (int q = 0; q < 4; ++q) {
    h[q] = (f16)vv[q];
    if (NP == 2) mm[q] = (f16)(vv[q] - (float)h[q]);
  }
  ((half4*)out)[i] = h;
  if (NP == 2) ((half4*)(out + planeStride))[i] = mm;
}

// fp32 [Mr,Nc] -> NP fp16 planes of the TRANSPOSE [Nc,Mr]
template <int NP>
__global__ __launch_bounds__(256) void split_t(const float* __restrict__ in,
                                               f16* __restrict__ out, int Mr,
                                               int Nc, long planeStride) {
  __shared__ float Ls[64][65];
  const int i0 = blockIdx.y * 64;  // row tile in source
  const int j0 = blockIdx.x * 64;  // col tile in source
  const int t = threadIdx.x;
  const int r = t >> 4;
  const int c = (t & 15) * 4;
#pragma unroll
  for (int i = 0; i < 4; ++i) {
    const float4 v =
        *(const float4*)&in[(size_t)(i0 + r + i * 16) * Nc + j0 + c];
    Ls[r + i * 16][c + 0] = v.x;
    Ls[r + i * 16][c + 1] = v.y;
    Ls[r + i * 16][c + 2] = v.z;
    Ls[r + i * 16][c + 3] = v.w;
  }
  __syncthreads();
#pragma unroll
  for (int i = 0; i < 4; ++i) {
    const int r2 = r + i * 16;  // source col (= dest row local)
    half4 h, mm;
#pragma unroll
    for (int q = 0; q < 4; ++q) {
      const float v = Ls[c + q][r2];
      h[q] = (f16)v;
      if (NP == 2) mm[q] = (f16)(v - (float)h[q]);
    }
    *(half4*)&out[(size_t)(j0 + r2) * Mr + i0 + c] = h;
    if (NP == 2)
      *(half4*)&out[planeStride + (size_t)(j0 + r2) * Mr + i0 + c] = mm;
  }
}

// row softmax of fp32 [1024,4096] chunk -> fp16 P plane at rowOff
__global__ __launch_bounds__(256) void softmax_p16(const float* __restrict__ L,
                                                   f16* __restrict__ P,
                                                   int rowOff) {
  const int row = blockIdx.x;
  const float* p = L + (size_t)row * 4096;
  f16* o = P + (size_t)(rowOff + row) * 4096;
  const int tid = threadIdx.x;
  __shared__ float red[8];

  float m = -INFINITY;
  for (int i = tid * 4; i < 4096; i += 1024) {
    const float4 v = *reinterpret_cast<const float4*>(&p[i]);
    m = fmaxf(fmaxf(fmaxf(v.x, v.y), fmaxf(v.z, v.w)), m);
  }
#pragma unroll
  for (int off = 32; off > 0; off >>= 1) m = fmaxf(m, __shfl_xor(m, off));
  if ((tid & 63) == 0) red[tid >> 6] = m;
  __syncthreads();
  m = fmaxf(fmaxf(red[0], red[1]), fmaxf(red[2], red[3]));

  float s = 0.f;
  for (int i = tid * 4; i < 4096; i += 1024) {
    const float4 v = *reinterpret_cast<const float4*>(&p[i]);
    s += expf(v.x - m) + expf(v.y - m) + expf(v.z - m) + expf(v.w - m);
  }
#pragma unroll
  for (int off = 32; off > 0; off >>= 1) s += __shfl_xor(s, off);
  if ((tid & 63) == 0) red[4 + (tid >> 6)] = s;
  __syncthreads();
  s = red[4] + red[5] + red[6] + red[7];
  const float inv = 1.0f / s;

  for (int i = tid * 4; i < 4096; i += 1024) {
    const float4 v = *reinterpret_cast<const float4*>(&p[i]);
    half4 h;
    h[0] = (f16)(expf(v.x - m) * inv);
    h[1] = (f16)(expf(v.y - m) * inv);
    h[2] = (f16)(expf(v.z - m) * inv);
    h[3] = (f16)(expf(v.w - m) * inv);
    *(half4*)&o[i] = h;
  }
}

extern "C" void kernel_launch(void* const* d_in, const int* in_sizes, int n_in,
                              void* d_out, int out_size, void* d_ws,
                              size_t ws_size, hipStream_t stream) {
  const float* X = (const float*)d_in[0];   // [4096,1024]
  const float* R = (const float*)d_in[1];   // [1024,1024]
  const float* Wl = (const float*)d_in[2];  // [1024,1024] (out,in)
  const float* bias = (const float*)d_in[3];
  float* out = (float*)d_out;

  const int Bq = 4096, D = 1024;
  const size_t MiB = 1 << 20;
  uint8_t* w8 = (uint8_t*)d_ws;
  // 100 MiB layout (round-0 proved >= 100 MiB exists), with overlap reuse:
  f16* Xp = (f16*)(w8);             // [0,16)   2 planes [4096,1024]
  f16* Xtp = (f16*)(w8 + 16 * MiB); // [16,24)  1 plane  [1024,4096]
  f16* Rp = (f16*)(w8 + 24 * MiB);  // [24,28)  2 planes [1024,1024]
  f16* Rtp = (f16*)(w8 + 28 * MiB); // [28,32)  2 planes
  f16* Awp = (f16*)(w8 + 24 * MiB); // [24,32)  1 plane [4096,1024] (after G1)
  f16* Mtp = (f16*)(w8 + 32 * MiB); // [32,36)  2 planes [1024,1024]
  f16* Wp = (f16*)(w8 + 32 * MiB);  // [32,34)  1 plane (after G2, Mtp dead)
  f16* Tp = (f16*)(w8 + 36 * MiB);  // [36,52)  2 planes [4096,1024]
  float* Lb = (float*)(w8 + 52 * MiB);  // [52,68) fp32 [1024,4096]
  f16* Pp = (f16*)(w8 + 68 * MiB);      // [68,100) 1 plane [4096,4096]

  const long sR = (long)D * D, sX = (long)Bq * D;

  split_n<2><<<D * D / 1024, 256, 0, stream>>>(R, Rp, sR, D * D / 4);
  split_t<2><<<dim3(D / 64, D / 64), 256, 0, stream>>>(R, Rtp, D, D, sR);
  split_n<2><<<Bq * D / 1024, 256, 0, stream>>>(X, Xp, sX, Bq * D / 4);
  split_t<1><<<dim3(D / 64, Bq / 64), 256, 0, stream>>>(X, Xtp, Bq, D, 0);

  // Mt = R^T R^T = Rt . R^T_op   -> split2 planes
  gemm_mp<2, 1, false><<<dim3(D / 128, D / 128), 256, 0, stream>>>(
      Rtp, Rp, Mtp, nullptr, D, D, D, sR, sR, sR, 1.f);
  // T = X . M = Xp . Mtp^T_op    -> split2 planes
  gemm_mp<2, 1, false><<<dim3(D / 128, Bq / 128), 256, 0, stream>>>(
      Xp, Mtp, Tp, nullptr, Bq, D, D, sX, sR, sX, 1.f);
  // W plane (after G2: Mtp region dead)
  split_n<1><<<D * D / 1024, 256, 0, stream>>>(Wl, Wp, 0, D * D / 4);

  // logits chunks (1024 rows) + softmax -> fp16 P plane
  for (int c = 0; c < 4; ++c) {
    gemm_mp<2, 0, false><<<dim3(Bq / 128, 1024 / 128), 256, 0, stream>>>(
        Tp + (size_t)c * 1024 * D, Xp, Lb, nullptr, 1024, Bq, D, sX, sX, 0,
        0.03125f);
    softmax_p16<<<1024, 256, 0, stream>>>(Lb, Pp, c * 1024);
  }

  // Aw = P . X = Pp . Xtp^T_op   -> fp16 plane
  gemm_mp<1, 2, false><<<dim3(D / 128, Bq / 128), 256, 0, stream>>>(
      Pp, Xtp, Awp, nullptr, Bq, D, Bq, 0, 0, 0, 1.f);
  // out = Aw . W^T + bias        -> fp32
  gemm_mp<1, 0, true><<<dim3(D / 128, Bq / 128), 256, 0, stream>>>(
      Awp, Wp, out, bias, Bq, D, D, 0, 0, 0, 1.f);
}

// Round 3
// 330.299 us; speedup vs baseline: 3.8851x; 1.2943x over previous
//
#include <hip/hip_runtime.h>
#include <math.h>
#include <stdint.h>

using f16 = _Float16;
using half8 = __attribute__((ext_vector_type(8))) f16;
using half4 = __attribute__((ext_vector_type(4))) f16;
using f32x4 = __attribute__((ext_vector_type(4))) float;

__device__ __forceinline__ void gl_lds16(const f16* g, f16* l) {
  __builtin_amdgcn_global_load_lds(
      (const __attribute__((address_space(1))) void*)g,
      (__attribute__((address_space(3))) void*)l, 16, 0, 0);
}

// C[M,N] = scale * sum_planes Aplane[M,K] . Bplane[N,K]^T  (+bias)
// NP: planes per operand (2 -> hh+hm+mh Markidis split). TN: tile N (64/128).
// EPI: 0 = fp32 out (+scale,+bias), 1 = split2 f16 planes, 2 = f16 plane.
template <int NP, int TN, int EPI, bool BIASF, int MINW>
__global__ __launch_bounds__(256, MINW) void gemm_mp(
    const f16* __restrict__ Ap, const f16* __restrict__ Bp,
    void* __restrict__ Cv, const float* __restrict__ bias, int M, int N, int K,
    long sAp, long sBp, long sCp, float scale) {
  constexpr int FR = (TN == 128) ? 4 : 2;  // row frags per wave
  constexpr int FC = 4;                    // col frags per wave
  constexpr int AG = NP * 512;             // A granules (16B) per K-step
  constexpr int BPG = TN * 4;              // B granules per plane
  __shared__ f16 As[NP * 128 * 32];
  __shared__ f16 Bs[NP * TN * 32];
  const int tid = threadIdx.x;
  const int lane = tid & 63;
  const int wave = tid >> 6;
  const int wr = (TN == 128) ? (wave >> 1) * 64 : wave * 32;
  const int wc = (TN == 128) ? (wave & 1) * 64 : 0;

  // XCD-aware bijective swizzle (all grids are multiples of 8 blocks)
  const int nwg = gridDim.x * gridDim.y;
  int bid = blockIdx.y * gridDim.x + blockIdx.x;
  bid = (bid & 7) * (nwg >> 3) + (bid >> 3);
  const int bm = (bid / gridDim.x) * 128;
  const int bn = (bid % gridDim.x) * TN;

  // fragment LDS offsets (half elements), XOR-swizzled granules
  int aoff[NP][FR], boff[NP][FC];
#pragma unroll
  for (int p = 0; p < NP; ++p) {
#pragma unroll
    for (int m = 0; m < FR; ++m) {
      const int row = wr + m * 16 + (lane & 15);
      const int kga = (lane >> 4) ^ ((row >> 1) & 3);
      aoff[p][m] = (p * 512 + row * 4 + kga) * 8;
    }
#pragma unroll
    for (int n = 0; n < FC; ++n) {
      const int col = wc + n * 16 + (lane & 15);
      const int kgb = (lane >> 4) ^ ((col >> 1) & 3);
      boff[p][n] = (p * BPG + col * 4 + kgb) * 8;
    }
  }

  f32x4 acc[FR][FC];
#pragma unroll
  for (int m = 0; m < FR; ++m)
#pragma unroll
    for (int n = 0; n < FC; ++n) acc[m][n] = (f32x4){0.f, 0.f, 0.f, 0.f};

  for (int k0 = 0; k0 < K; k0 += 32) {
#pragma unroll
    for (int i = 0; i < (NP * (512 + TN * 4)) / 256; ++i) {
      const int g0 = i * 256 + wave * 64;  // wave-uniform granule base
      const bool isB = g0 >= AG;           // never straddles within a wave
      const int ga0 = g0 - (isB ? AG : 0);
      const int ga = ga0 + lane;
      const int pl = isB ? (ga / BPG) : (ga >> 9);
      const int gp = isB ? (ga % BPG) : (ga & 511);
      const int r = gp >> 2;
      const int cg = (gp & 3) ^ ((r >> 1) & 3);
      const f16* gs = (isB ? Bp + (size_t)pl * sBp + (size_t)(bn + r) * K
                           : Ap + (size_t)pl * sAp + (size_t)(bm + r) * K) +
                      k0 + cg * 8;
      f16* ld = (isB ? Bs : As) + (size_t)ga0 * 8;
      gl_lds16(gs, ld);
    }
    __syncthreads();

    half8 af[NP][FR], bf[NP][FC];
#pragma unroll
    for (int p = 0; p < NP; ++p) {
#pragma unroll
      for (int m = 0; m < FR; ++m) af[p][m] = *(const half8*)&As[aoff[p][m]];
#pragma unroll
      for (int n = 0; n < FC; ++n) bf[p][n] = *(const half8*)&Bs[boff[p][n]];
    }
#pragma unroll
    for (int m = 0; m < FR; ++m) {
#pragma unroll
      for (int n = 0; n < FC; ++n) {
        acc[m][n] = __builtin_amdgcn_mfma_f32_16x16x32_f16(af[0][m], bf[0][n],
                                                           acc[m][n], 0, 0, 0);
        if (NP == 2) {
          acc[m][n] = __builtin_amdgcn_mfma_f32_16x16x32_f16(
              af[0][m], bf[1][n], acc[m][n], 0, 0, 0);
          acc[m][n] = __builtin_amdgcn_mfma_f32_16x16x32_f16(
              af[1][m], bf[0][n], acc[m][n], 0, 0, 0);
        }
      }
    }
    __syncthreads();
  }

  // epilogue. C/D layout: col = lane&15, row = (lane>>4)*4 + q
#pragma unroll
  for (int m = 0; m < FR; ++m) {
#pragma unroll
    for (int n = 0; n < FC; ++n) {
      const int col = bn + wc + n * 16 + (lane & 15);
      const float bv = BIASF ? bias[col] : 0.f;
#pragma unroll
      for (int q = 0; q < 4; ++q) {
        const int row = bm + wr + m * 16 + (lane >> 4) * 4 + q;
        float v = acc[m][n][q] * scale;
        if (EPI == 0) {
          ((float*)Cv)[(size_t)row * N + col] = v + bv;
        } else if (EPI == 1) {
          f16* C = (f16*)Cv;
          const f16 h = (f16)v;
          C[(size_t)row * N + col] = h;
          C[sCp + (size_t)row * N + col] = (f16)(v - (float)h);
        } else {
          ((f16*)Cv)[(size_t)row * N + col] = (f16)v;
        }
      }
    }
  }
}

// fp32 -> NP fp16 planes (elementwise), one float4 per thread
template <int NP>
__global__ __launch_bounds__(256) void split_n(const float* __restrict__ in,
                                               f16* __restrict__ out,
                                               long planeStride, int n4) {
  const int i = blockIdx.x * 256 + threadIdx.x;
  if (i >= n4) return;
  const float4 v = ((const float4*)in)[i];
  const float vv[4] = {v.x, v.y, v.z, v.w};
  half4 h, mm;
#pragma unroll
  for (int q = 0; q < 4; ++q) {
    h[q] = (f16)vv[q];
    if (NP == 2) mm[q] = (f16)(vv[q] - (float)h[q]);
  }
  ((half4*)out)[i] = h;
  if (NP == 2) ((half4*)(out + planeStride))[i] = mm;
}

// fp32 [Mr,Nc] -> NP fp16 planes of the TRANSPOSE [Nc,Mr]
template <int NP>
__global__ __launch_bounds__(256) void split_t(const float* __restrict__ in,
                                               f16* __restrict__ out, int Mr,
                                               int Nc, long planeStride) {
  __shared__ float Ls[64][65];
  const int i0 = blockIdx.y * 64;
  const int j0 = blockIdx.x * 64;
  const int t = threadIdx.x;
  const int r = t >> 4;
  const int c = (t & 15) * 4;
#pragma unroll
  for (int i = 0; i < 4; ++i) {
    const float4 v =
        *(const float4*)&in[(size_t)(i0 + r + i * 16) * Nc + j0 + c];
    Ls[r + i * 16][c + 0] = v.x;
    Ls[r + i * 16][c + 1] = v.y;
    Ls[r + i * 16][c + 2] = v.z;
    Ls[r + i * 16][c + 3] = v.w;
  }
  __syncthreads();
#pragma unroll
  for (int i = 0; i < 4; ++i) {
    const int r2 = r + i * 16;
    half4 h, mm;
#pragma unroll
    for (int q = 0; q < 4; ++q) {
      const float v = Ls[c + q][r2];
      h[q] = (f16)v;
      if (NP == 2) mm[q] = (f16)(v - (float)h[q]);
    }
    *(half4*)&out[(size_t)(j0 + r2) * Mr + i0 + c] = h;
    if (NP == 2)
      *(half4*)&out[planeStride + (size_t)(j0 + r2) * Mr + i0 + c] = mm;
  }
}

// full-row softmax fp32 [4096] -> f16 P row; one block per row
__global__ __launch_bounds__(256) void softmax_p16(const float* __restrict__ L,
                                                   f16* __restrict__ P) {
  const int row = blockIdx.x;
  const float* p = L + (size_t)row * 4096;
  f16* o = P + (size_t)row * 4096;
  const int tid = threadIdx.x;
  __shared__ float red[8];

  float m = -INFINITY;
  for (int i = tid * 4; i < 4096; i += 1024) {
    const float4 v = *reinterpret_cast<const float4*>(&p[i]);
    m = fmaxf(fmaxf(fmaxf(v.x, v.y), fmaxf(v.z, v.w)), m);
  }
#pragma unroll
  for (int off = 32; off > 0; off >>= 1) m = fmaxf(m, __shfl_xor(m, off));
  if ((tid & 63) == 0) red[tid >> 6] = m;
  __syncthreads();
  m = fmaxf(fmaxf(red[0], red[1]), fmaxf(red[2], red[3]));

  float s = 0.f;
  for (int i = tid * 4; i < 4096; i += 1024) {
    const float4 v = *reinterpret_cast<const float4*>(&p[i]);
    s += expf(v.x - m) + expf(v.y - m) + expf(v.z - m) + expf(v.w - m);
  }
#pragma unroll
  for (int off = 32; off > 0; off >>= 1) s += __shfl_xor(s, off);
  if ((tid & 63) == 0) red[4 + (tid >> 6)] = s;
  __syncthreads();
  s = red[4] + red[5] + red[6] + red[7];
  const float inv = 1.0f / s;

  for (int i = tid * 4; i < 4096; i += 1024) {
    const float4 v = *reinterpret_cast<const float4*>(&p[i]);
    half4 h;
    h[0] = (f16)(expf(v.x - m) * inv);
    h[1] = (f16)(expf(v.y - m) * inv);
    h[2] = (f16)(expf(v.z - m) * inv);
    h[3] = (f16)(expf(v.w - m) * inv);
    *(half4*)&o[i] = h;
  }
}

extern "C" void kernel_launch(void* const* d_in, const int* in_sizes, int n_in,
                              void* d_out, int out_size, void* d_ws,
                              size_t ws_size, hipStream_t stream) {
  const float* X = (const float*)d_in[0];   // [4096,1024]
  const float* R = (const float*)d_in[1];   // [1024,1024]
  const float* Wl = (const float*)d_in[2];  // [1024,1024] (out,in)
  const float* bias = (const float*)d_in[3];
  float* out = (float*)d_out;

  const int Bq = 4096, D = 1024;
  const size_t MiB = 1 << 20;
  uint8_t* w8 = (uint8_t*)d_ws;
  // lifetimes: Xp,Tp dead after G4 (P overwrites); Rp/Rtp/Mtp dead before L;
  // L dead after softmax (Xh/Yt overwrite).
  f16* Xp = (f16*)(w8);              // [0,16)  2 planes [4096,1024]
  f16* Tp = (f16*)(w8 + 16 * MiB);   // [16,32) 2 planes [4096,1024]
  f16* Pp = (f16*)(w8);              // [0,32)  1 plane  [4096,4096] (post-SM)
  f16* Wp = (f16*)(w8 + 32 * MiB);   // [32,34) 1 plane  [1024,1024]
  f16* Rp = (f16*)(w8 + 36 * MiB);   // [36,40) 2 planes
  f16* Rtp = (f16*)(w8 + 40 * MiB);  // [40,44) 2 planes
  f16* Mtp = (f16*)(w8 + 44 * MiB);  // [44,48) 2 planes
  float* L = (float*)(w8 + 36 * MiB);  // [36,100) fp32 [4096,4096]
  f16* Xh = (f16*)(w8 + 36 * MiB);   // [36,44) 1 plane [4096,1024] (post-SM)
  f16* Yt = (f16*)(w8 + 44 * MiB);   // [44,52) 1 plane [1024,4096] (post-SM)

  const long sR = (long)D * D, sX = (long)Bq * D;
  const dim3 blk(256);

  split_n<2><<<D * D / 1024, blk, 0, stream>>>(R, Rp, sR, D * D / 4);
  split_t<2><<<dim3(D / 64, D / 64), blk, 0, stream>>>(R, Rtp, D, D, sR);
  split_n<2><<<Bq * D / 1024, blk, 0, stream>>>(X, Xp, sX, Bq * D / 4);
  split_n<1><<<D * D / 1024, blk, 0, stream>>>(Wl, Wp, 0, D * D / 4);

  // G1: Mt = Rt . R^T  (split2 out), grid 128
  gemm_mp<2, 64, 1, false, 2><<<dim3(D / 64, D / 128), blk, 0, stream>>>(
      Rtp, Rp, Mtp, nullptr, D, D, D, sR, sR, sR, 1.f);
  // G2: T = Xp . Mt^T  (split2 out), grid 512
  gemm_mp<2, 64, 1, false, 2><<<dim3(D / 64, Bq / 128), blk, 0, stream>>>(
      Xp, Mtp, Tp, nullptr, Bq, D, D, sX, sR, sX, 1.f);
  // G4: L = scale * Tp . Xp^T  (fp32), grid 1024 -> 4 blocks/CU
  gemm_mp<2, 128, 0, false, 2><<<dim3(Bq / 128, Bq / 128), blk, 0, stream>>>(
      Tp, Xp, L, nullptr, Bq, Bq, D, sX, sX, 0, 0.03125f);
  // softmax rows -> f16 P (overwrites Xp/Tp)
  softmax_p16<<<dim3(Bq), blk, 0, stream>>>(L, Pp);
  // re-split X (L region is dead now)
  split_n<1><<<Bq * D / 1024, blk, 0, stream>>>(X, Xh, 0, Bq * D / 4);
  // G3: Yt = Wp . Xh^T = (X W^T)^T  (f16), grid 512
  gemm_mp<1, 64, 2, false, 4><<<dim3(Bq / 64, D / 128), blk, 0, stream>>>(
      Wp, Xh, Yt, nullptr, D, Bq, D, 0, 0, 0, 1.f);
  // G5: out = Pp . Yt^T + bias  (fp32), grid 512
  gemm_mp<1, 64, 0, true, 4><<<dim3(D / 64, Bq / 128), blk, 0, stream>>>(
      Pp, Yt, out, bias, Bq, D, Bq, 0, 0, 0, 1.f);
}

// Round 4
// 284.546 us; speedup vs baseline: 4.5098x; 1.1608x over previous
//
#include <hip/hip_runtime.h>
#include <math.h>
#include <stdint.h>

using f16 = _Float16;
using half8 = __attribute__((ext_vector_type(8))) f16;
using half4 = __attribute__((ext_vector_type(4))) f16;
using f32x4 = __attribute__((ext_vector_type(4))) float;

__device__ __forceinline__ void gl_lds16(const f16* g, f16* l) {
  __builtin_amdgcn_global_load_lds(
      (const __attribute__((address_space(1))) void*)g,
      (__attribute__((address_space(3))) void*)l, 16, 0, 0);
}

// ---------------------------------------------------------------------------
// Deep-pipelined GEMM (T2+T3+T4+T5): C[M,N] = scale * sum_prod A . B^T
// BM=BN=128, 8 waves (wave tile 32x64), 3 LDS buffers, counted vmcnt.
// NP=2: Markidis split2, K-step 32, planes at stride sAp/sBp, prods hh+hm+mh.
// NP=1: single plane, K-step 64 staged as two 32-K chunks, prods (0,0)+(1,1).
// EPI: 0 = fp32 out (+scale,+bias), 1 = split2 f16 planes, 2 = f16 plane.
// ---------------------------------------------------------------------------
template <int NP, int EPI, bool BIASF>
__global__ __launch_bounds__(512, 2) void gemm_dp(
    const f16* __restrict__ Ap, const f16* __restrict__ Bp,
    void* __restrict__ Cv, const float* __restrict__ bias, int M, int N, int K,
    long sAp, long sBp, long sCp, float scale) {
  // buffer = [A: 2pl x 128row x 4gran | B: 2pl x 128 x 4gran], gran = 16B
  __shared__ f16 lds[3 * 2048 * 8];
  const int tid = threadIdx.x;
  const int lane = tid & 63;
  const int wave = tid >> 6;
  const int wr = (wave >> 1) * 32;
  const int wc = (wave & 1) * 64;

  const int nwg = gridDim.x * gridDim.y;
  int bid = blockIdx.y * gridDim.x + blockIdx.x;
  bid = (bid & 7) * (nwg >> 3) + (bid >> 3);  // XCD-aware (nwg % 8 == 0)
  const int bm = (bid / gridDim.x) * 128;
  const int bn = (bid % gridDim.x) * 128;

  constexpr int KSTEP = (NP == 2) ? 32 : 64;
  const int nt = K / KSTEP;

  // stage part i (0..3) of tile t into buffer t%3 (2 gl_lds per thread each
  // pair of calls; 4 calls = full 64KB tile). Wave-uniform LDS base.
  auto stage = [&](int t, int i) {
    const int g0 = i * 512 + wave * 64;  // uniform granule base
    const int ga = g0 + lane;
    const bool isB = ga >= 1024;
    const int gl = ga & 1023;
    const int pl = gl >> 9;
    const int gp = gl & 511;
    const int r = gp >> 2;
    const int cg = (gp & 3) ^ ((r >> 1) & 3);  // XOR-swizzled source granule
    const long sP = (NP == 2) ? (isB ? sBp : sAp) : 0;
    const int kOff = (NP == 2) ? 0 : pl * 32;
    const f16* gs = (isB ? Bp : Ap) + (size_t)pl * sP +
                    (size_t)((isB ? bn : bm) + r) * K + t * KSTEP + kOff +
                    cg * 8;
    gl_lds16(gs, &lds[((size_t)(t % 3) * 2048 + g0) * 8]);
  };

  // fragment ds_read offsets (halfs, within one buffer), swizzled
  int aoff[2][2], boff[2][4];
#pragma unroll
  for (int pl = 0; pl < 2; ++pl) {
#pragma unroll
    for (int m = 0; m < 2; ++m) {
      const int row = wr + m * 16 + (lane & 15);
      const int kg = (lane >> 4) ^ ((row >> 1) & 3);
      aoff[pl][m] = (pl * 512 + row * 4 + kg) * 8;
    }
#pragma unroll
    for (int n = 0; n < 4; ++n) {
      const int col = wc + n * 16 + (lane & 15);
      const int kg = (lane >> 4) ^ ((col >> 1) & 3);
      boff[pl][n] = (1024 + pl * 512 + col * 4 + kg) * 8;
    }
  }

  f32x4 acc[2][4];
#pragma unroll
  for (int m = 0; m < 2; ++m)
#pragma unroll
    for (int n = 0; n < 4; ++n) acc[m][n] = (f32x4){0.f, 0.f, 0.f, 0.f};

  // prologue: prime tiles 0 and 1
#pragma unroll
  for (int i = 0; i < 4; ++i) stage(0, i);
#pragma unroll
  for (int i = 0; i < 4; ++i) stage(1, i);

  for (int t = 0; t < nt; ++t) {
    const f16* buf = &lds[(size_t)(t % 3) * 2048 * 8];
    // tile boundary: ensure tile t landed; keep next tile's 4 loads in flight
    if (t + 1 < nt)
      asm volatile("s_waitcnt vmcnt(4)" ::: "memory");
    else
      asm volatile("s_waitcnt vmcnt(0)" ::: "memory");
    asm volatile("s_barrier" ::: "memory");

    // ---- phase 1: A frags + B frags {0,1}
    half8 af[2][2], b0[2][2];
#pragma unroll
    for (int pl = 0; pl < 2; ++pl) {
#pragma unroll
      for (int m = 0; m < 2; ++m) af[pl][m] = *(const half8*)&buf[aoff[pl][m]];
#pragma unroll
      for (int j = 0; j < 2; ++j) b0[pl][j] = *(const half8*)&buf[boff[pl][j]];
    }
    if (t + 2 < nt) {
      stage(t + 2, 0);
      stage(t + 2, 1);
    }
    __builtin_amdgcn_sched_barrier(0);
    asm volatile("s_barrier" ::: "memory");
    asm volatile("s_waitcnt lgkmcnt(0)" ::: "memory");
    __builtin_amdgcn_sched_barrier(0);
    __builtin_amdgcn_s_setprio(1);
#pragma unroll
    for (int m = 0; m < 2; ++m) {
#pragma unroll
      for (int j = 0; j < 2; ++j) {
        acc[m][j] = __builtin_amdgcn_mfma_f32_16x16x32_f16(af[0][m], b0[0][j],
                                                           acc[m][j], 0, 0, 0);
        if (NP == 2) {
          acc[m][j] = __builtin_amdgcn_mfma_f32_16x16x32_f16(
              af[0][m], b0[1][j], acc[m][j], 0, 0, 0);
          acc[m][j] = __builtin_amdgcn_mfma_f32_16x16x32_f16(
              af[1][m], b0[0][j], acc[m][j], 0, 0, 0);
        } else {
          acc[m][j] = __builtin_amdgcn_mfma_f32_16x16x32_f16(
              af[1][m], b0[1][j], acc[m][j], 0, 0, 0);
        }
      }
    }
    __builtin_amdgcn_s_setprio(0);
    __builtin_amdgcn_sched_barrier(0);
    asm volatile("s_barrier" ::: "memory");

    // ---- phase 2: B frags {2,3}
    half8 b1[2][2];
#pragma unroll
    for (int pl = 0; pl < 2; ++pl)
#pragma unroll
      for (int j = 0; j < 2; ++j)
        b1[pl][j] = *(const half8*)&buf[boff[pl][2 + j]];
    if (t + 2 < nt) {
      stage(t + 2, 2);
      stage(t + 2, 3);
    }
    __builtin_amdgcn_sched_barrier(0);
    asm volatile("s_barrier" ::: "memory");
    asm volatile("s_waitcnt lgkmcnt(0)" ::: "memory");
    __builtin_amdgcn_sched_barrier(0);
    __builtin_amdgcn_s_setprio(1);
#pragma unroll
    for (int m = 0; m < 2; ++m) {
#pragma unroll
      for (int j = 0; j < 2; ++j) {
        acc[m][2 + j] = __builtin_amdgcn_mfma_f32_16x16x32_f16(
            af[0][m], b1[0][j], acc[m][2 + j], 0, 0, 0);
        if (NP == 2) {
          acc[m][2 + j] = __builtin_amdgcn_mfma_f32_16x16x32_f16(
              af[0][m], b1[1][j], acc[m][2 + j], 0, 0, 0);
          acc[m][2 + j] = __builtin_amdgcn_mfma_f32_16x16x32_f16(
              af[1][m], b1[0][j], acc[m][2 + j], 0, 0, 0);
        } else {
          acc[m][2 + j] = __builtin_amdgcn_mfma_f32_16x16x32_f16(
              af[1][m], b1[1][j], acc[m][2 + j], 0, 0, 0);
        }
      }
    }
    __builtin_amdgcn_s_setprio(0);
    __builtin_amdgcn_sched_barrier(0);
    // no trailing barrier: tile-boundary {vmcnt; s_barrier} follows
  }

  // epilogue. C/D layout: col = lane&15, row = (lane>>4)*4 + q
#pragma unroll
  for (int m = 0; m < 2; ++m) {
#pragma unroll
    for (int n = 0; n < 4; ++n) {
      const int col = bn + wc + n * 16 + (lane & 15);
      const float bv = BIASF ? bias[col] : 0.f;
#pragma unroll
      for (int q = 0; q < 4; ++q) {
        const int row = bm + wr + m * 16 + (lane >> 4) * 4 + q;
        float v = acc[m][n][q] * scale;
        if (EPI == 0) {
          ((float*)Cv)[(size_t)row * N + col] = v + bv;
        } else if (EPI == 1) {
          f16* C = (f16*)Cv;
          const f16 h = (f16)v;
          C[(size_t)row * N + col] = h;
          C[sCp + (size_t)row * N + col] = (f16)(v - (float)h);
        } else {
          ((f16*)Cv)[(size_t)row * N + col] = (f16)v;
        }
      }
    }
  }
}

// ---------------------------------------------------------------------------
// Round-3 2-barrier kernel, kept for the tiny G1 (grid 128)
// ---------------------------------------------------------------------------
template <int NP, int TN, int EPI, bool BIASF, int MINW>
__global__ __launch_bounds__(256, MINW) void gemm_mp(
    const f16* __restrict__ Ap, const f16* __restrict__ Bp,
    void* __restrict__ Cv, const float* __restrict__ bias, int M, int N, int K,
    long sAp, long sBp, long sCp, float scale) {
  constexpr int FR = (TN == 128) ? 4 : 2;
  constexpr int FC = 4;
  constexpr int AG = NP * 512;
  constexpr int BPG = TN * 4;
  __shared__ f16 As[NP * 128 * 32];
  __shared__ f16 Bs[NP * TN * 32];
  const int tid = threadIdx.x;
  const int lane = tid & 63;
  const int wave = tid >> 6;
  const int wr = (TN == 128) ? (wave >> 1) * 64 : wave * 32;
  const int wc = (TN == 128) ? (wave & 1) * 64 : 0;

  const int nwg = gridDim.x * gridDim.y;
  int bid = blockIdx.y * gridDim.x + blockIdx.x;
  bid = (bid & 7) * (nwg >> 3) + (bid >> 3);
  const int bm = (bid / gridDim.x) * 128;
  const int bn = (bid % gridDim.x) * TN;

  int aoff[NP][FR], boff[NP][FC];
#pragma unroll
  for (int p = 0; p < NP; ++p) {
#pragma unroll
    for (int m = 0; m < FR; ++m) {
      const int row = wr + m * 16 + (lane & 15);
      const int kga = (lane >> 4) ^ ((row >> 1) & 3);
      aoff[p][m] = (p * 512 + row * 4 + kga) * 8;
    }
#pragma unroll
    for (int n = 0; n < FC; ++n) {
      const int col = wc + n * 16 + (lane & 15);
      const int kgb = (lane >> 4) ^ ((col >> 1) & 3);
      boff[p][n] = (p * BPG + col * 4 + kgb) * 8;
    }
  }

  f32x4 acc[FR][FC];
#pragma unroll
  for (int m = 0; m < FR; ++m)
#pragma unroll
    for (int n = 0; n < FC; ++n) acc[m][n] = (f32x4){0.f, 0.f, 0.f, 0.f};

  for (int k0 = 0; k0 < K; k0 += 32) {
#pragma unroll
    for (int i = 0; i < (NP * (512 + TN * 4)) / 256; ++i) {
      const int g0 = i * 256 + wave * 64;
      const bool isB = g0 >= AG;
      const int ga0 = g0 - (isB ? AG : 0);
      const int ga = ga0 + lane;
      const int pl = isB ? (ga / BPG) : (ga >> 9);
      const int gp = isB ? (ga % BPG) : (ga & 511);
      const int r = gp >> 2;
      const int cg = (gp & 3) ^ ((r >> 1) & 3);
      const f16* gs = (isB ? Bp + (size_t)pl * sBp + (size_t)(bn + r) * K
                           : Ap + (size_t)pl * sAp + (size_t)(bm + r) * K) +
                      k0 + cg * 8;
      f16* ld = (isB ? Bs : As) + (size_t)ga0 * 8;
      gl_lds16(gs, ld);
    }
    __syncthreads();

    half8 af[NP][FR], bf[NP][FC];
#pragma unroll
    for (int p = 0; p < NP; ++p) {
#pragma unroll
      for (int m = 0; m < FR; ++m) af[p][m] = *(const half8*)&As[aoff[p][m]];
#pragma unroll
      for (int n = 0; n < FC; ++n) bf[p][n] = *(const half8*)&Bs[boff[p][n]];
    }
#pragma unroll
    for (int m = 0; m < FR; ++m) {
#pragma unroll
      for (int n = 0; n < FC; ++n) {
        acc[m][n] = __builtin_amdgcn_mfma_f32_16x16x32_f16(af[0][m], bf[0][n],
                                                           acc[m][n], 0, 0, 0);
        if (NP == 2) {
          acc[m][n] = __builtin_amdgcn_mfma_f32_16x16x32_f16(
              af[0][m], bf[1][n], acc[m][n], 0, 0, 0);
          acc[m][n] = __builtin_amdgcn_mfma_f32_16x16x32_f16(
              af[1][m], bf[0][n], acc[m][n], 0, 0, 0);
        }
      }
    }
    __syncthreads();
  }

#pragma unroll
  for (int m = 0; m < FR; ++m) {
#pragma unroll
    for (int n = 0; n < FC; ++n) {
      const int col = bn + wc + n * 16 + (lane & 15);
      const float bv = BIASF ? bias[col] : 0.f;
#pragma unroll
      for (int q = 0; q < 4; ++q) {
        const int row = bm + wr + m * 16 + (lane >> 4) * 4 + q;
        float v = acc[m][n][q] * scale;
        if (EPI == 0) {
          ((float*)Cv)[(size_t)row * N + col] = v + bv;
        } else if (EPI == 1) {
          f16* C = (f16*)Cv;
          const f16 h = (f16)v;
          C[(size_t)row * N + col] = h;
          C[sCp + (size_t)row * N + col] = (f16)(v - (float)h);
        } else {
          ((f16*)Cv)[(size_t)row * N + col] = (f16)v;
        }
      }
    }
  }
}

// fp32 -> NP fp16 planes (elementwise)
template <int NP>
__global__ __launch_bounds__(256) void split_n(const float* __restrict__ in,
                                               f16* __restrict__ out,
                                               long planeStride, int n4) {
  const int i = blockIdx.x * 256 + threadIdx.x;
  if (i >= n4) return;
  const float4 v = ((const float4*)in)[i];
  const float vv[4] = {v.x, v.y, v.z, v.w};
  half4 h, mm;
#pragma unroll
  for (int q = 0; q < 4; ++q) {
    h[q] = (f16)vv[q];
    if (NP == 2) mm[q] = (f16)(vv[q] - (float)h[q]);
  }
  ((half4*)out)[i] = h;
  if (NP == 2) ((half4*)(out + planeStride))[i] = mm;
}

// fp32 [Mr,Nc] -> NP fp16 planes of the TRANSPOSE [Nc,Mr]
template <int NP>
__global__ __launch_bounds__(256) void split_t(const float* __restrict__ in,
                                               f16* __restrict__ out, int Mr,
                                               int Nc, long planeStride) {
  __shared__ float Ls[64][65];
  const int i0 = blockIdx.y * 64;
  const int j0 = blockIdx.x * 64;
  const int t = threadIdx.x;
  const int r = t >> 4;
  const int c = (t & 15) * 4;
#pragma unroll
  for (int i = 0; i < 4; ++i) {
    const float4 v =
        *(const float4*)&in[(size_t)(i0 + r + i * 16) * Nc + j0 + c];
    Ls[r + i * 16][c + 0] = v.x;
    Ls[r + i * 16][c + 1] = v.y;
    Ls[r + i * 16][c + 2] = v.z;
    Ls[r + i * 16][c + 3] = v.w;
  }
  __syncthreads();
#pragma unroll
  for (int i = 0; i < 4; ++i) {
    const int r2 = r + i * 16;
    half4 h, mm;
#pragma unroll
    for (int q = 0; q < 4; ++q) {
      const float v = Ls[c + q][r2];
      h[q] = (f16)v;
      if (NP == 2) mm[q] = (f16)(v - (float)h[q]);
    }
    *(half4*)&out[(size_t)(j0 + r2) * Mr + i0 + c] = h;
    if (NP == 2)
      *(half4*)&out[planeStride + (size_t)(j0 + r2) * Mr + i0 + c] = mm;
  }
}

// full-row softmax fp32 [4096] -> f16 P row; one block per row
__global__ __launch_bounds__(256) void softmax_p16(const float* __restrict__ L,
                                                   f16* __restrict__ P) {
  const int row = blockIdx.x;
  const float* p = L + (size_t)row * 4096;
  f16* o = P + (size_t)row * 4096;
  const int tid = threadIdx.x;
  __shared__ float red[8];

  float m = -INFINITY;
  for (int i = tid * 4; i < 4096; i += 1024) {
    const float4 v = *reinterpret_cast<const float4*>(&p[i]);
    m = fmaxf(fmaxf(fmaxf(v.x, v.y), fmaxf(v.z, v.w)), m);
  }
#pragma unroll
  for (int off = 32; off > 0; off >>= 1) m = fmaxf(m, __shfl_xor(m, off));
  if ((tid & 63) == 0) red[tid >> 6] = m;
  __syncthreads();
  m = fmaxf(fmaxf(red[0], red[1]), fmaxf(red[2], red[3]));

  float s = 0.f;
  for (int i = tid * 4; i < 4096; i += 1024) {
    const float4 v = *reinterpret_cast<const float4*>(&p[i]);
    s += expf(v.x - m) + expf(v.y - m) + expf(v.z - m) + expf(v.w - m);
  }
#pragma unroll
  for (int off = 32; off > 0; off >>= 1) s += __shfl_xor(s, off);
  if ((tid & 63) == 0) red[4 + (tid >> 6)] = s;
  __syncthreads();
  s = red[4] + red[5] + red[6] + red[7];
  const float inv = 1.0f / s;

  for (int i = tid * 4; i < 4096; i += 1024) {
    const float4 v = *reinterpret_cast<const float4*>(&p[i]);
    half4 h;
    h[0] = (f16)(expf(v.x - m) * inv);
    h[1] = (f16)(expf(v.y - m) * inv);
    h[2] = (f16)(expf(v.z - m) * inv);
    h[3] = (f16)(expf(v.w - m) * inv);
    *(half4*)&o[i] = h;
  }
}

extern "C" void kernel_launch(void* const* d_in, const int* in_sizes, int n_in,
                              void* d_out, int out_size, void* d_ws,
                              size_t ws_size, hipStream_t stream) {
  const float* X = (const float*)d_in[0];   // [4096,1024]
  const float* R = (const float*)d_in[1];   // [1024,1024]
  const float* Wl = (const float*)d_in[2];  // [1024,1024] (out,in)
  const float* bias = (const float*)d_in[3];
  float* out = (float*)d_out;

  const int Bq = 4096, D = 1024;
  const size_t MiB = 1 << 20;
  uint8_t* w8 = (uint8_t*)d_ws;
  f16* Xp = (f16*)(w8);              // [0,16)  2 planes [4096,1024]
  f16* Tp = (f16*)(w8 + 16 * MiB);   // [16,32) 2 planes [4096,1024]
  f16* Pp = (f16*)(w8);              // [0,32)  1 plane  [4096,4096] (post-SM)
  f16* Wp = (f16*)(w8 + 32 * MiB);   // [32,34) 1 plane  [1024,1024]
  f16* Rp = (f16*)(w8 + 36 * MiB);   // [36,40) 2 planes
  f16* Rtp = (f16*)(w8 + 40 * MiB);  // [40,44) 2 planes
  f16* Mtp = (f16*)(w8 + 44 * MiB);  // [44,48) 2 planes
  float* L = (float*)(w8 + 36 * MiB);  // [36,100) fp32 [4096,4096]
  f16* Xh = (f16*)(w8 + 36 * MiB);   // [36,44) 1 plane [4096,1024] (post-SM)
  f16* Yt = (f16*)(w8 + 44 * MiB);   // [44,52) 1 plane [1024,4096] (post-SM)

  const long sR = (long)D * D, sX = (long)Bq * D;
  const dim3 blk(256), blk512(512);

  split_n<2><<<D * D / 1024, blk, 0, stream>>>(R, Rp, sR, D * D / 4);
  split_t<2><<<dim3(D / 64, D / 64), blk, 0, stream>>>(R, Rtp, D, D, sR);
  split_n<2><<<Bq * D / 1024, blk, 0, stream>>>(X, Xp, sX, Bq * D / 4);
  split_n<1><<<D * D / 1024, blk, 0, stream>>>(Wl, Wp, 0, D * D / 4);

  // G1: Mt = Rt . R^T  (split2 out), old kernel, grid 128
  gemm_mp<2, 64, 1, false, 2><<<dim3(D / 64, D / 128), blk, 0, stream>>>(
      Rtp, Rp, Mtp, nullptr, D, D, D, sR, sR, sR, 1.f);
  // G2: T = Xp . Mt^T  (split2 out), dp, grid 8x32=256
  gemm_dp<2, 1, false><<<dim3(D / 128, Bq / 128), blk512, 0, stream>>>(
      Xp, Mtp, Tp, nullptr, Bq, D, D, sX, sR, sX, 1.f);
  // G4: L = scale * Tp . Xp^T  (fp32), dp, grid 32x32=1024
  gemm_dp<2, 0, false><<<dim3(Bq / 128, Bq / 128), blk512, 0, stream>>>(
      Tp, Xp, L, nullptr, Bq, Bq, D, sX, sX, 0, 0.03125f);
  // softmax rows -> f16 P (overwrites Xp/Tp)
  softmax_p16<<<dim3(Bq), blk, 0, stream>>>(L, Pp);
  // re-split X (L region dead now)
  split_n<1><<<Bq * D / 1024, blk, 0, stream>>>(X, Xh, 0, Bq * D / 4);
  // G3: Yt = Wp . Xh^T = (X W^T)^T  (f16), dp, grid 32x8=256
  gemm_dp<1, 2, false><<<dim3(Bq / 128, D / 128), blk512, 0, stream>>>(
      Wp, Xh, Yt, nullptr, D, Bq, D, 0, 0, 0, 1.f);
  // G5: out = Pp . Yt^T + bias  (fp32), dp, grid 8x32=256
  gemm_dp<1, 0, true><<<dim3(D / 128, Bq / 128), blk512, 0, stream>>>(
      Pp, Yt, out, bias, Bq, D, Bq, 0, 0, 0, 1.f);
}

// Round 5
// 259.175 us; speedup vs baseline: 4.9512x; 1.0979x over previous
//
#include <hip/hip_runtime.h>
#include <math.h>
#include <stdint.h>

using f16 = _Float16;
using half8 = __attribute__((ext_vector_type(8))) f16;
using half4 = __attribute__((ext_vector_type(4))) f16;
using f32x4 = __attribute__((ext_vector_type(4))) float;

__device__ __forceinline__ void gl_lds16(const f16* g, f16* l) {
  __builtin_amdgcn_global_load_lds(
      (const __attribute__((address_space(1))) void*)g,
      (__attribute__((address_space(3))) void*)l, 16, 0, 0);
}

// ---------------------------------------------------------------------------
// 256^2-tile 4-phase Markidis GEMM (T2+T3+T4+T5), for the big logits GEMM.
// C[M,N] = scale * (A.B^T hh+hm+mh over split2 planes), fp32 out.
// 8 waves (wave tile 128x64), KSTEP=32, double-buffered 128KB LDS.
// ---------------------------------------------------------------------------
__global__ __launch_bounds__(512, 2) void gemm_q2(
    const f16* __restrict__ Ap, const f16* __restrict__ Bp,
    float* __restrict__ C, int N, int K, long sAp, long sBp, float scale) {
  // buffer (granules of 16B): [A: pl*1024 + r*4 + kg | B: 2048 + same]
  __shared__ f16 lds[2 * 4096 * 8];
  const int tid = threadIdx.x;
  const int lane = tid & 63;
  const int wave = tid >> 6;
  const int wr = (wave >> 2) * 128;
  const int wc = (wave & 3) * 64;

  const int nwg = gridDim.x * gridDim.y;
  int bid = blockIdx.y * gridDim.x + blockIdx.x;
  bid = (bid & 7) * (nwg >> 3) + (bid >> 3);  // XCD-aware (nwg % 8 == 0)
  const int bm = (bid / gridDim.x) * 256;
  const int bn = (bid % gridDim.x) * 256;

  const int nt = K / 32;

  // stage part i (0..7) of tile t: 512 granules, 1 gl_lds/thread.
  auto stage = [&](int t, int i) {
    const int g0 = i * 512 + wave * 64;  // wave-uniform granule base
    const int ga = g0 + lane;
    const bool isB = ga >= 2048;
    const int gl = ga & 2047;
    const int pl = gl >> 10;
    const int gp = gl & 1023;
    const int r = gp >> 2;
    const int cg = (gp & 3) ^ ((r >> 1) & 3);  // XOR-swizzled source granule
    const f16* gs = (isB ? Bp + (size_t)pl * sBp + (size_t)(bn + r) * K
                         : Ap + (size_t)pl * sAp + (size_t)(bm + r) * K) +
                    t * 32 + cg * 8;
    gl_lds16(gs, &lds[((size_t)(t & 1) * 4096 + g0) * 8]);
  };

  // fragment ds_read offsets (halfs within buffer), swizzled
  int aoff[2][8], boff[2][4];
#pragma unroll
  for (int pl = 0; pl < 2; ++pl) {
#pragma unroll
    for (int fr = 0; fr < 8; ++fr) {
      const int row = wr + fr * 16 + (lane & 15);
      const int kg = (lane >> 4) ^ ((row >> 1) & 3);
      aoff[pl][fr] = (pl * 1024 + row * 4 + kg) * 8;
    }
#pragma unroll
    for (int fc = 0; fc < 4; ++fc) {
      const int col = wc + fc * 16 + (lane & 15);
      const int kg = (lane >> 4) ^ ((col >> 1) & 3);
      boff[pl][fc] = (2048 + pl * 1024 + col * 4 + kg) * 8;
    }
  }

  f32x4 acc[8][4];
#pragma unroll
  for (int m = 0; m < 8; ++m)
#pragma unroll
    for (int n = 0; n < 4; ++n) acc[m][n] = (f32x4){0.f, 0.f, 0.f, 0.f};

  half8 af[2][4], bf[2][2];

#define LOAD_A(h)                                            \
  _Pragma("unroll") for (int pl = 0; pl < 2; ++pl)           \
      _Pragma("unroll") for (int i = 0; i < 4; ++i) af[pl][i] = \
          *(const half8*)&buf[aoff[pl][(h) * 4 + i]];
#define LOAD_B(h)                                            \
  _Pragma("unroll") for (int pl = 0; pl < 2; ++pl)           \
      _Pragma("unroll") for (int j = 0; j < 2; ++j) bf[pl][j] = \
          *(const half8*)&buf[boff[pl][(h) * 2 + j]];
#define MFMA_Q(ah, bh)                                                        \
  _Pragma("unroll") for (int i = 0; i < 4; ++i) _Pragma("unroll") for (int j = \
                                                                          0;  \
                                                                       j < 2; \
                                                                       ++j) { \
    acc[(ah) * 4 + i][(bh) * 2 + j] = __builtin_amdgcn_mfma_f32_16x16x32_f16( \
        af[0][i], bf[0][j], acc[(ah) * 4 + i][(bh) * 2 + j], 0, 0, 0);        \
    acc[(ah) * 4 + i][(bh) * 2 + j] = __builtin_amdgcn_mfma_f32_16x16x32_f16( \
        af[0][i], bf[1][j], acc[(ah) * 4 + i][(bh) * 2 + j], 0, 0, 0);        \
    acc[(ah) * 4 + i][(bh) * 2 + j] = __builtin_amdgcn_mfma_f32_16x16x32_f16( \
        af[1][i], bf[0][j], acc[(ah) * 4 + i][(bh) * 2 + j], 0, 0, 0);        \
  }
#define PHASE_TAIL()                                    \
  __builtin_amdgcn_sched_barrier(0);                    \
  asm volatile("s_barrier" ::: "memory");               \
  asm volatile("s_waitcnt lgkmcnt(0)" ::: "memory");    \
  __builtin_amdgcn_sched_barrier(0);                    \
  __builtin_amdgcn_s_setprio(1);
#define PHASE_END()                                     \
  __builtin_amdgcn_s_setprio(0);                        \
  __builtin_amdgcn_sched_barrier(0);                    \
  asm volatile("s_barrier" ::: "memory");

  // prologue: prime tile 0
#pragma unroll
  for (int i = 0; i < 8; ++i) stage(0, i);

  for (int t = 0; t < nt; ++t) {
    const f16* buf = &lds[(size_t)(t & 1) * 4096 * 8];
    asm volatile("s_waitcnt vmcnt(0)" ::: "memory");
    asm volatile("s_barrier" ::: "memory");
    const bool pf = (t + 1 < nt);

    // phase 1: quadrant (A0,B0)
    LOAD_A(0);
    LOAD_B(0);
    if (pf) { stage(t + 1, 0); stage(t + 1, 1); stage(t + 1, 2); }
    PHASE_TAIL();
    MFMA_Q(0, 0);
    PHASE_END();

    // phase 2: quadrant (A0,B1)
    LOAD_B(1);
    if (pf) { stage(t + 1, 3); stage(t + 1, 4); stage(t + 1, 5); }
    PHASE_TAIL();
    MFMA_Q(0, 1);
    PHASE_END();

    // phase 3: quadrant (A1,B1)
    LOAD_A(1);
    if (pf) { stage(t + 1, 6); stage(t + 1, 7); }
    PHASE_TAIL();
    MFMA_Q(1, 1);
    PHASE_END();

    // phase 4: quadrant (A1,B0) (re-read B0)
    LOAD_B(0);
    PHASE_TAIL();
    MFMA_Q(1, 0);
    __builtin_amdgcn_s_setprio(0);
    __builtin_amdgcn_sched_barrier(0);
    // boundary {vmcnt(0); s_barrier} at loop top serves as phase-4 end barrier
  }
#undef LOAD_A
#undef LOAD_B
#undef MFMA_Q
#undef PHASE_TAIL
#undef PHASE_END

  // epilogue. C/D layout: col = lane&15, row = (lane>>4)*4 + q
#pragma unroll
  for (int m = 0; m < 8; ++m) {
#pragma unroll
    for (int n = 0; n < 4; ++n) {
      const int col = bn + wc + n * 16 + (lane & 15);
#pragma unroll
      for (int q = 0; q < 4; ++q) {
        const int row = bm + wr + m * 16 + (lane >> 4) * 4 + q;
        C[(size_t)row * N + col] = acc[m][n][q] * scale;
      }
    }
  }
}

// ---------------------------------------------------------------------------
// 128^2 deep-pipelined GEMM (round 4), used for G2/G3/G5.
// ---------------------------------------------------------------------------
template <int NP, int EPI, bool BIASF>
__global__ __launch_bounds__(512, 2) void gemm_dp(
    const f16* __restrict__ Ap, const f16* __restrict__ Bp,
    void* __restrict__ Cv, const float* __restrict__ bias, int M, int N, int K,
    long sAp, long sBp, long sCp, float scale) {
  __shared__ f16 lds[3 * 2048 * 8];
  const int tid = threadIdx.x;
  const int lane = tid & 63;
  const int wave = tid >> 6;
  const int wr = (wave >> 1) * 32;
  const int wc = (wave & 1) * 64;

  const int nwg = gridDim.x * gridDim.y;
  int bid = blockIdx.y * gridDim.x + blockIdx.x;
  bid = (bid & 7) * (nwg >> 3) + (bid >> 3);
  const int bm = (bid / gridDim.x) * 128;
  const int bn = (bid % gridDim.x) * 128;

  constexpr int KSTEP = (NP == 2) ? 32 : 64;
  const int nt = K / KSTEP;

  auto stage = [&](int t, int i) {
    const int g0 = i * 512 + wave * 64;
    const int ga = g0 + lane;
    const bool isB = ga >= 1024;
    const int gl = ga & 1023;
    const int pl = gl >> 9;
    const int gp = gl & 511;
    const int r = gp >> 2;
    const int cg = (gp & 3) ^ ((r >> 1) & 3);
    const long sP = (NP == 2) ? (isB ? sBp : sAp) : 0;
    const int kOff = (NP == 2) ? 0 : pl * 32;
    const f16* gs = (isB ? Bp : Ap) + (size_t)pl * sP +
                    (size_t)((isB ? bn : bm) + r) * K + t * KSTEP + kOff +
                    cg * 8;
    gl_lds16(gs, &lds[((size_t)(t % 3) * 2048 + g0) * 8]);
  };

  int aoff[2][2], boff[2][4];
#pragma unroll
  for (int pl = 0; pl < 2; ++pl) {
#pragma unroll
    for (int m = 0; m < 2; ++m) {
      const int row = wr + m * 16 + (lane & 15);
      const int kg = (lane >> 4) ^ ((row >> 1) & 3);
      aoff[pl][m] = (pl * 512 + row * 4 + kg) * 8;
    }
#pragma unroll
    for (int n = 0; n < 4; ++n) {
      const int col = wc + n * 16 + (lane & 15);
      const int kg = (lane >> 4) ^ ((col >> 1) & 3);
      boff[pl][n] = (1024 + pl * 512 + col * 4 + kg) * 8;
    }
  }

  f32x4 acc[2][4];
#pragma unroll
  for (int m = 0; m < 2; ++m)
#pragma unroll
    for (int n = 0; n < 4; ++n) acc[m][n] = (f32x4){0.f, 0.f, 0.f, 0.f};

#pragma unroll
  for (int i = 0; i < 4; ++i) stage(0, i);
#pragma unroll
  for (int i = 0; i < 4; ++i) stage(1, i);

  for (int t = 0; t < nt; ++t) {
    const f16* buf = &lds[(size_t)(t % 3) * 2048 * 8];
    if (t + 1 < nt)
      asm volatile("s_waitcnt vmcnt(4)" ::: "memory");
    else
      asm volatile("s_waitcnt vmcnt(0)" ::: "memory");
    asm volatile("s_barrier" ::: "memory");

    half8 af[2][2], b0[2][2];
#pragma unroll
    for (int pl = 0; pl < 2; ++pl) {
#pragma unroll
      for (int m = 0; m < 2; ++m) af[pl][m] = *(const half8*)&buf[aoff[pl][m]];
#pragma unroll
      for (int j = 0; j < 2; ++j) b0[pl][j] = *(const half8*)&buf[boff[pl][j]];
    }
    if (t + 2 < nt) {
      stage(t + 2, 0);
      stage(t + 2, 1);
    }
    __builtin_amdgcn_sched_barrier(0);
    asm volatile("s_barrier" ::: "memory");
    asm volatile("s_waitcnt lgkmcnt(0)" ::: "memory");
    __builtin_amdgcn_sched_barrier(0);
    __builtin_amdgcn_s_setprio(1);
#pragma unroll
    for (int m = 0; m < 2; ++m) {
#pragma unroll
      for (int j = 0; j < 2; ++j) {
        acc[m][j] = __builtin_amdgcn_mfma_f32_16x16x32_f16(af[0][m], b0[0][j],
                                                           acc[m][j], 0, 0, 0);
        if (NP == 2) {
          acc[m][j] = __builtin_amdgcn_mfma_f32_16x16x32_f16(
              af[0][m], b0[1][j], acc[m][j], 0, 0, 0);
          acc[m][j] = __builtin_amdgcn_mfma_f32_16x16x32_f16(
              af[1][m], b0[0][j], acc[m][j], 0, 0, 0);
        } else {
          acc[m][j] = __builtin_amdgcn_mfma_f32_16x16x32_f16(
              af[1][m], b0[1][j], acc[m][j], 0, 0, 0);
        }
      }
    }
    __builtin_amdgcn_s_setprio(0);
    __builtin_amdgcn_sched_barrier(0);
    asm volatile("s_barrier" ::: "memory");

    half8 b1[2][2];
#pragma unroll
    for (int pl = 0; pl < 2; ++pl)
#pragma unroll
      for (int j = 0; j < 2; ++j)
        b1[pl][j] = *(const half8*)&buf[boff[pl][2 + j]];
    if (t + 2 < nt) {
      stage(t + 2, 2);
      stage(t + 2, 3);
    }
    __builtin_amdgcn_sched_barrier(0);
    asm volatile("s_barrier" ::: "memory");
    asm volatile("s_waitcnt lgkmcnt(0)" ::: "memory");
    __builtin_amdgcn_sched_barrier(0);
    __builtin_amdgcn_s_setprio(1);
#pragma unroll
    for (int m = 0; m < 2; ++m) {
#pragma unroll
      for (int j = 0; j < 2; ++j) {
        acc[m][2 + j] = __builtin_amdgcn_mfma_f32_16x16x32_f16(
            af[0][m], b1[0][j], acc[m][2 + j], 0, 0, 0);
        if (NP == 2) {
          acc[m][2 + j] = __builtin_amdgcn_mfma_f32_16x16x32_f16(
              af[0][m], b1[1][j], acc[m][2 + j], 0, 0, 0);
          acc[m][2 + j] = __builtin_amdgcn_mfma_f32_16x16x32_f16(
              af[1][m], b1[0][j], acc[m][2 + j], 0, 0, 0);
        } else {
          acc[m][2 + j] = __builtin_amdgcn_mfma_f32_16x16x32_f16(
              af[1][m], b1[1][j], acc[m][2 + j], 0, 0, 0);
        }
      }
    }
    __builtin_amdgcn_s_setprio(0);
    __builtin_amdgcn_sched_barrier(0);
  }

#pragma unroll
  for (int m = 0; m < 2; ++m) {
#pragma unroll
    for (int n = 0; n < 4; ++n) {
      const int col = bn + wc + n * 16 + (lane & 15);
      const float bv = BIASF ? bias[col] : 0.f;
#pragma unroll
      for (int q = 0; q < 4; ++q) {
        const int row = bm + wr + m * 16 + (lane >> 4) * 4 + q;
        float v = acc[m][n][q] * scale;
        if (EPI == 0) {
          ((float*)Cv)[(size_t)row * N + col] = v + bv;
        } else if (EPI == 1) {
          f16* C = (f16*)Cv;
          const f16 h = (f16)v;
          C[(size_t)row * N + col] = h;
          C[sCp + (size_t)row * N + col] = (f16)(v - (float)h);
        } else {
          ((f16*)Cv)[(size_t)row * N + col] = (f16)v;
        }
      }
    }
  }
}

// ---------------------------------------------------------------------------
// Round-3 2-barrier kernel, kept for the tiny G1 (grid 128)
// ---------------------------------------------------------------------------
template <int NP, int TN, int EPI, bool BIASF, int MINW>
__global__ __launch_bounds__(256, MINW) void gemm_mp(
    const f16* __restrict__ Ap, const f16* __restrict__ Bp,
    void* __restrict__ Cv, const float* __restrict__ bias, int M, int N, int K,
    long sAp, long sBp, long sCp, float scale) {
  constexpr int FR = (TN == 128) ? 4 : 2;
  constexpr int FC = 4;
  constexpr int AG = NP * 512;
  constexpr int BPG = TN * 4;
  __shared__ f16 As[NP * 128 * 32];
  __shared__ f16 Bs[NP * TN * 32];
  const int tid = threadIdx.x;
  const int lane = tid & 63;
  const int wave = tid >> 6;
  const int wr = (TN == 128) ? (wave >> 1) * 64 : wave * 32;
  const int wc = (TN == 128) ? (wave & 1) * 64 : 0;

  const int nwg = gridDim.x * gridDim.y;
  int bid = blockIdx.y * gridDim.x + blockIdx.x;
  bid = (bid & 7) * (nwg >> 3) + (bid >> 3);
  const int bm = (bid / gridDim.x) * 128;
  const int bn = (bid % gridDim.x) * TN;

  int aoff[NP][FR], boff[NP][FC];
#pragma unroll
  for (int p = 0; p < NP; ++p) {
#pragma unroll
    for (int m = 0; m < FR; ++m) {
      const int row = wr + m * 16 + (lane & 15);
      const int kga = (lane >> 4) ^ ((row >> 1) & 3);
      aoff[p][m] = (p * 512 + row * 4 + kga) * 8;
    }
#pragma unroll
    for (int n = 0; n < FC; ++n) {
      const int col = wc + n * 16 + (lane & 15);
      const int kgb = (lane >> 4) ^ ((col >> 1) & 3);
      boff[p][n] = (p * BPG + col * 4 + kgb) * 8;
    }
  }

  f32x4 acc[FR][FC];
#pragma unroll
  for (int m = 0; m < FR; ++m)
#pragma unroll
    for (int n = 0; n < FC; ++n) acc[m][n] = (f32x4){0.f, 0.f, 0.f, 0.f};

  for (int k0 = 0; k0 < K; k0 += 32) {
#pragma unroll
    for (int i = 0; i < (NP * (512 + TN * 4)) / 256; ++i) {
      const int g0 = i * 256 + wave * 64;
      const bool isB = g0 >= AG;
      const int ga0 = g0 - (isB ? AG : 0);
      const int ga = ga0 + lane;
      const int pl = isB ? (ga / BPG) : (ga >> 9);
      const int gp = isB ? (ga % BPG) : (ga & 511);
      const int r = gp >> 2;
      const int cg = (gp & 3) ^ ((r >> 1) & 3);
      const f16* gs = (isB ? Bp + (size_t)pl * sBp + (size_t)(bn + r) * K
                           : Ap + (size_t)pl * sAp + (size_t)(bm + r) * K) +
                      k0 + cg * 8;
      f16* ld = (isB ? Bs : As) + (size_t)ga0 * 8;
      gl_lds16(gs, ld);
    }
    __syncthreads();

    half8 af[NP][FR], bf[NP][FC];
#pragma unroll
    for (int p = 0; p < NP; ++p) {
#pragma unroll
      for (int m = 0; m < FR; ++m) af[p][m] = *(const half8*)&As[aoff[p][m]];
#pragma unroll
      for (int n = 0; n < FC; ++n) bf[p][n] = *(const half8*)&Bs[boff[p][n]];
    }
#pragma unroll
    for (int m = 0; m < FR; ++m) {
#pragma unroll
      for (int n = 0; n < FC; ++n) {
        acc[m][n] = __builtin_amdgcn_mfma_f32_16x16x32_f16(af[0][m], bf[0][n],
                                                           acc[m][n], 0, 0, 0);
        if (NP == 2) {
          acc[m][n] = __builtin_amdgcn_mfma_f32_16x16x32_f16(
              af[0][m], bf[1][n], acc[m][n], 0, 0, 0);
          acc[m][n] = __builtin_amdgcn_mfma_f32_16x16x32_f16(
              af[1][m], bf[0][n], acc[m][n], 0, 0, 0);
        }
      }
    }
    __syncthreads();
  }

#pragma unroll
  for (int m = 0; m < FR; ++m) {
#pragma unroll
    for (int n = 0; n < FC; ++n) {
      const int col = bn + wc + n * 16 + (lane & 15);
      const float bv = BIASF ? bias[col] : 0.f;
#pragma unroll
      for (int q = 0; q < 4; ++q) {
        const int row = bm + wr + m * 16 + (lane >> 4) * 4 + q;
        float v = acc[m][n][q] * scale;
        if (EPI == 0) {
          ((float*)Cv)[(size_t)row * N + col] = v + bv;
        } else if (EPI == 1) {
          f16* C = (f16*)Cv;
          const f16 h = (f16)v;
          C[(size_t)row * N + col] = h;
          C[sCp + (size_t)row * N + col] = (f16)(v - (float)h);
        } else {
          ((f16*)Cv)[(size_t)row * N + col] = (f16)v;
        }
      }
    }
  }
}

// fp32 -> NP fp16 planes (elementwise)
template <int NP>
__global__ __launch_bounds__(256) void split_n(const float* __restrict__ in,
                                               f16* __restrict__ out,
                                               long planeStride, int n4) {
  const int i = blockIdx.x * 256 + threadIdx.x;
  if (i >= n4) return;
  const float4 v = ((const float4*)in)[i];
  const float vv[4] = {v.x, v.y, v.z, v.w};
  half4 h, mm;
#pragma unroll
  for (int q = 0; q < 4; ++q) {
    h[q] = (f16)vv[q];
    if (NP == 2) mm[q] = (f16)(vv[q] - (float)h[q]);
  }
  ((half4*)out)[i] = h;
  if (NP == 2) ((half4*)(out + planeStride))[i] = mm;
}

// fp32 [Mr,Nc] -> NP fp16 planes of the TRANSPOSE [Nc,Mr]
template <int NP>
__global__ __launch_bounds__(256) void split_t(const float* __restrict__ in,
                                               f16* __restrict__ out, int Mr,
                                               int Nc, long planeStride) {
  __shared__ float Ls[64][65];
  const int i0 = blockIdx.y * 64;
  const int j0 = blockIdx.x * 64;
  const int t = threadIdx.x;
  const int r = t >> 4;
  const int c = (t & 15) * 4;
#pragma unroll
  for (int i = 0; i < 4; ++i) {
    const float4 v =
        *(const float4*)&in[(size_t)(i0 + r + i * 16) * Nc + j0 + c];
    Ls[r + i * 16][c + 0] = v.x;
    Ls[r + i * 16][c + 1] = v.y;
    Ls[r + i * 16][c + 2] = v.z;
    Ls[r + i * 16][c + 3] = v.w;
  }
  __syncthreads();
#pragma unroll
  for (int i = 0; i < 4; ++i) {
    const int r2 = r + i * 16;
    half4 h, mm;
#pragma unroll
    for (int q = 0; q < 4; ++q) {
      const float v = Ls[c + q][r2];
      h[q] = (f16)v;
      if (NP == 2) mm[q] = (f16)(v - (float)h[q]);
    }
    *(half4*)&out[(size_t)(j0 + r2) * Mr + i0 + c] = h;
    if (NP == 2)
      *(half4*)&out[planeStride + (size_t)(j0 + r2) * Mr + i0 + c] = mm;
  }
}

// full-row softmax fp32 [4096] -> f16 P row; one block per row
__global__ __launch_bounds__(256) void softmax_p16(const float* __restrict__ L,
                                                   f16* __restrict__ P) {
  const int row = blockIdx.x;
  const float* p = L + (size_t)row * 4096;
  f16* o = P + (size_t)row * 4096;
  const int tid = threadIdx.x;
  __shared__ float red[8];

  float m = -INFINITY;
  for (int i = tid * 4; i < 4096; i += 1024) {
    const float4 v = *reinterpret_cast<const float4*>(&p[i]);
    m = fmaxf(fmaxf(fmaxf(v.x, v.y), fmaxf(v.z, v.w)), m);
  }
#pragma unroll
  for (int off = 32; off > 0; off >>= 1) m = fmaxf(m, __shfl_xor(m, off));
  if ((tid & 63) == 0) red[tid >> 6] = m;
  __syncthreads();
  m = fmaxf(fmaxf(red[0], red[1]), fmaxf(red[2], red[3]));

  float s = 0.f;
  for (int i = tid * 4; i < 4096; i += 1024) {
    const float4 v = *reinterpret_cast<const float4*>(&p[i]);
    s += expf(v.x - m) + expf(v.y - m) + expf(v.z - m) + expf(v.w - m);
  }
#pragma unroll
  for (int off = 32; off > 0; off >>= 1) s += __shfl_xor(s, off);
  if ((tid & 63) == 0) red[4 + (tid >> 6)] = s;
  __syncthreads();
  s = red[4] + red[5] + red[6] + red[7];
  const float inv = 1.0f / s;

  for (int i = tid * 4; i < 4096; i += 1024) {
    const float4 v = *reinterpret_cast<const float4*>(&p[i]);
    half4 h;
    h[0] = (f16)(expf(v.x - m) * inv);
    h[1] = (f16)(expf(v.y - m) * inv);
    h[2] = (f16)(expf(v.z - m) * inv);
    h[3] = (f16)(expf(v.w - m) * inv);
    *(half4*)&o[i] = h;
  }
}

extern "C" void kernel_launch(void* const* d_in, const int* in_sizes, int n_in,
                              void* d_out, int out_size, void* d_ws,
                              size_t ws_size, hipStream_t stream) {
  const float* X = (const float*)d_in[0];   // [4096,1024]
  const float* R = (const float*)d_in[1];   // [1024,1024]
  const float* Wl = (const float*)d_in[2];  // [1024,1024] (out,in)
  const float* bias = (const float*)d_in[3];
  float* out = (float*)d_out;

  const int Bq = 4096, D = 1024;
  const size_t MiB = 1 << 20;
  uint8_t* w8 = (uint8_t*)d_ws;
  f16* Xp = (f16*)(w8);              // [0,16)  2 planes [4096,1024]
  f16* Tp = (f16*)(w8 + 16 * MiB);   // [16,32) 2 planes [4096,1024]
  f16* Pp = (f16*)(w8);              // [0,32)  1 plane  [4096,4096] (post-SM)
  f16* Wp = (f16*)(w8 + 32 * MiB);   // [32,34) 1 plane  [1024,1024]
  f16* Rp = (f16*)(w8 + 36 * MiB);   // [36,40) 2 planes
  f16* Rtp = (f16*)(w8 + 40 * MiB);  // [40,44) 2 planes
  f16* Mtp = (f16*)(w8 + 44 * MiB);  // [44,48) 2 planes
  float* L = (float*)(w8 + 36 * MiB);  // [36,100) fp32 [4096,4096]
  f16* Xh = (f16*)(w8 + 36 * MiB);   // [36,44) 1 plane [4096,1024] (post-SM)
  f16* Yt = (f16*)(w8 + 44 * MiB);   // [44,52) 1 plane [1024,4096] (post-SM)

  const long sR = (long)D * D, sX = (long)Bq * D;
  const dim3 blk(256), blk512(512);

  split_n<2><<<D * D / 1024, blk, 0, stream>>>(R, Rp, sR, D * D / 4);
  split_t<2><<<dim3(D / 64, D / 64), blk, 0, stream>>>(R, Rtp, D, D, sR);
  split_n<2><<<Bq * D / 1024, blk, 0, stream>>>(X, Xp, sX, Bq * D / 4);
  split_n<1><<<D * D / 1024, blk, 0, stream>>>(Wl, Wp, 0, D * D / 4);

  // G1: Mt = Rt . R^T  (split2 out), grid 128
  gemm_mp<2, 64, 1, false, 2><<<dim3(D / 64, D / 128), blk, 0, stream>>>(
      Rtp, Rp, Mtp, nullptr, D, D, D, sR, sR, sR, 1.f);
  // G2: T = Xp . Mt^T  (split2 out), dp, grid 256
  gemm_dp<2, 1, false><<<dim3(D / 128, Bq / 128), blk512, 0, stream>>>(
      Xp, Mtp, Tp, nullptr, Bq, D, D, sX, sR, sX, 1.f);
  // G4: L = scale * Tp . Xp^T  (fp32), 256^2 4-phase, grid 16x16=256
  gemm_q2<<<dim3(Bq / 256, Bq / 256), blk512, 0, stream>>>(
      Tp, Xp, L, Bq, D, sX, sX, 0.03125f);
  // softmax rows -> f16 P (overwrites Xp/Tp)
  softmax_p16<<<dim3(Bq), blk, 0, stream>>>(L, Pp);
  // re-split X (L region dead now)
  split_n<1><<<Bq * D / 1024, blk, 0, stream>>>(X, Xh, 0, Bq * D / 4);
  // G3: Yt = Wp . Xh^T = (X W^T)^T  (f16), dp, grid 256
  gemm_dp<1, 2, false><<<dim3(Bq / 128, D / 128), blk512, 0, stream>>>(
      Wp, Xh, Yt, nullptr, D, Bq, D, 0, 0, 0, 1.f);
  // G5: out = Pp . Yt^T + bias  (fp32), dp, grid 256
  gemm_dp<1, 0, true><<<dim3(D / 128, Bq / 128), blk512, 0, stream>>>(
      Pp, Yt, out, bias, Bq, D, Bq, 0, 0, 0, 1.f);
}

// Round 6
// 246.129 us; speedup vs baseline: 5.2137x; 1.0530x over previous
//
#include <hip/hip_runtime.h>
#include <math.h>
#include <stdint.h>

using f16 = _Float16;
using half8 = __attribute__((ext_vector_type(8))) f16;
using half4 = __attribute__((ext_vector_type(4))) f16;
using f32x4 = __attribute__((ext_vector_type(4))) float;

__device__ __forceinline__ void gl_lds16(const f16* g, f16* l) {
  __builtin_amdgcn_global_load_lds(
      (const __attribute__((address_space(1))) void*)g,
      (__attribute__((address_space(3))) void*)l, 16, 0, 0);
}

// ---------------------------------------------------------------------------
// 256^2-tile Markidis GEMM, barrier-free inner tile (T2+T4+T5):
// C[M,N] = scale * (A.B^T hh+hm+mh over split2 planes), fp32 out.
// 8 waves (wave tile 128x64), KSTEP=32, double-buffered 128KB LDS.
// One s_barrier per K-tile; ds_reads pipelined one quadrant ahead so the
// compiler's counted lgkmcnt overlaps LDS reads with the MFMA quadrants.
// ---------------------------------------------------------------------------
__global__ __launch_bounds__(512, 2) void gemm_q2(
    const f16* __restrict__ Ap, const f16* __restrict__ Bp,
    float* __restrict__ C, int N, int K, long sAp, long sBp, float scale) {
  // buffer (granules of 16B): [A: pl*1024 + r*4 + kg | B: 2048 + same]
  __shared__ f16 lds[2 * 4096 * 8];
  const int tid = threadIdx.x;
  const int lane = tid & 63;
  const int wave = tid >> 6;
  const int wr = (wave >> 2) * 128;
  const int wc = (wave & 3) * 64;

  const int nwg = gridDim.x * gridDim.y;
  int bid = blockIdx.y * gridDim.x + blockIdx.x;
  bid = (bid & 7) * (nwg >> 3) + (bid >> 3);  // XCD-aware (nwg % 8 == 0)
  const int bm = (bid / gridDim.x) * 256;
  const int bn = (bid % gridDim.x) * 256;

  const int nt = K / 32;

  // stage part i (0..7) of tile t: 512 granules, 1 gl_lds/thread.
  auto stage = [&](int t, int i) {
    const int g0 = i * 512 + wave * 64;  // wave-uniform granule base
    const int ga = g0 + lane;
    const bool isB = ga >= 2048;
    const int gl = ga & 2047;
    const int pl = gl >> 10;
    const int gp = gl & 1023;
    const int r = gp >> 2;
    const int cg = (gp & 3) ^ ((r >> 1) & 3);  // XOR-swizzled source granule
    const f16* gs = (isB ? Bp + (size_t)pl * sBp + (size_t)(bn + r) * K
                         : Ap + (size_t)pl * sAp + (size_t)(bm + r) * K) +
                    t * 32 + cg * 8;
    gl_lds16(gs, &lds[((size_t)(t & 1) * 4096 + g0) * 8]);
  };

  // fragment ds_read offsets (halfs within buffer), swizzled
  int aoff[2][8], boff[2][4];
#pragma unroll
  for (int pl = 0; pl < 2; ++pl) {
#pragma unroll
    for (int fr = 0; fr < 8; ++fr) {
      const int row = wr + fr * 16 + (lane & 15);
      const int kg = (lane >> 4) ^ ((row >> 1) & 3);
      aoff[pl][fr] = (pl * 1024 + row * 4 + kg) * 8;
    }
#pragma unroll
    for (int fc = 0; fc < 4; ++fc) {
      const int col = wc + fc * 16 + (lane & 15);
      const int kg = (lane >> 4) ^ ((col >> 1) & 3);
      boff[pl][fc] = (2048 + pl * 1024 + col * 4 + kg) * 8;
    }
  }

  f32x4 acc[8][4];
#pragma unroll
  for (int m = 0; m < 8; ++m)
#pragma unroll
    for (int n = 0; n < 4; ++n) acc[m][n] = (f32x4){0.f, 0.f, 0.f, 0.f};

  half8 af0[2][4], af1[2][4], bf0[2][2], bf1[2][2];

#define LOAD_A(dst, h)                                          \
  _Pragma("unroll") for (int pl = 0; pl < 2; ++pl)              \
      _Pragma("unroll") for (int i = 0; i < 4; ++i) dst[pl][i] = \
          *(const half8*)&buf[aoff[pl][(h) * 4 + i]];
#define LOAD_B(dst, h)                                          \
  _Pragma("unroll") for (int pl = 0; pl < 2; ++pl)              \
      _Pragma("unroll") for (int j = 0; j < 2; ++j) dst[pl][j] = \
          *(const half8*)&buf[boff[pl][(h) * 2 + j]];
#define MFMA_Q(A, B, ah, bh)                                                  \
  _Pragma("unroll") for (int i = 0; i < 4; ++i)                               \
      _Pragma("unroll") for (int j = 0; j < 2; ++j) {                         \
    f32x4& c = acc[(ah) * 4 + i][(bh) * 2 + j];                               \
    c = __builtin_amdgcn_mfma_f32_16x16x32_f16(A[0][i], B[0][j], c, 0, 0, 0); \
    c = __builtin_amdgcn_mfma_f32_16x16x32_f16(A[0][i], B[1][j], c, 0, 0, 0); \
    c = __builtin_amdgcn_mfma_f32_16x16x32_f16(A[1][i], B[0][j], c, 0, 0, 0); \
  }
#define SBAR0() __builtin_amdgcn_sched_barrier(0)

  // prologue: prime tile 0
#pragma unroll
  for (int i = 0; i < 8; ++i) stage(0, i);

  for (int t = 0; t < nt; ++t) {
    const f16* buf = &lds[(size_t)(t & 1) * 4096 * 8];
    asm volatile("s_waitcnt vmcnt(0)" ::: "memory");
    asm volatile("s_barrier" ::: "memory");
    const bool pf = (t + 1 < nt);

    // issue Q1 frags + first half of next-tile staging
    LOAD_A(af0, 0);
    LOAD_B(bf0, 0);
    if (pf) { stage(t + 1, 0); stage(t + 1, 1); stage(t + 1, 2); stage(t + 1, 3); }
    SBAR0();
    LOAD_B(bf1, 1);  // prefetch Q2 frags
    SBAR0();
    __builtin_amdgcn_s_setprio(1);
    MFMA_Q(af0, bf0, 0, 0);
    __builtin_amdgcn_s_setprio(0);
    SBAR0();
    LOAD_A(af1, 1);  // prefetch Q3/Q4 A-frags
    if (pf) { stage(t + 1, 4); stage(t + 1, 5); stage(t + 1, 6); stage(t + 1, 7); }
    SBAR0();
    __builtin_amdgcn_s_setprio(1);
    MFMA_Q(af0, bf1, 0, 1);
    __builtin_amdgcn_s_setprio(0);
    SBAR0();
    LOAD_B(bf0, 0);  // re-read B0 for Q4 (keeps peak live frags low)
    SBAR0();
    __builtin_amdgcn_s_setprio(1);
    MFMA_Q(af1, bf1, 1, 1);
    __builtin_amdgcn_s_setprio(0);
    SBAR0();
    __builtin_amdgcn_s_setprio(1);
    MFMA_Q(af1, bf0, 1, 0);
    __builtin_amdgcn_s_setprio(0);
    SBAR0();
  }
#undef LOAD_A
#undef LOAD_B
#undef MFMA_Q
#undef SBAR0

  // epilogue. C/D layout: col = lane&15, row = (lane>>4)*4 + q
#pragma unroll
  for (int m = 0; m < 8; ++m) {
#pragma unroll
    for (int n = 0; n < 4; ++n) {
      const int col = bn + wc + n * 16 + (lane & 15);
#pragma unroll
      for (int q = 0; q < 4; ++q) {
        const int row = bm + wr + m * 16 + (lane >> 4) * 4 + q;
        C[(size_t)row * N + col] = acc[m][n][q] * scale;
      }
    }
  }
}

// ---------------------------------------------------------------------------
// 128^2 deep-pipelined GEMM (round 4), used for G2/G3/G5.
// ---------------------------------------------------------------------------
template <int NP, int EPI, bool BIASF>
__global__ __launch_bounds__(512, 2) void gemm_dp(
    const f16* __restrict__ Ap, const f16* __restrict__ Bp,
    void* __restrict__ Cv, const float* __restrict__ bias, int M, int N, int K,
    long sAp, long sBp, long sCp, float scale) {
  __shared__ f16 lds[3 * 2048 * 8];
  const int tid = threadIdx.x;
  const int lane = tid & 63;
  const int wave = tid >> 6;
  const int wr = (wave >> 1) * 32;
  const int wc = (wave & 1) * 64;

  const int nwg = gridDim.x * gridDim.y;
  int bid = blockIdx.y * gridDim.x + blockIdx.x;
  bid = (bid & 7) * (nwg >> 3) + (bid >> 3);
  const int bm = (bid / gridDim.x) * 128;
  const int bn = (bid % gridDim.x) * 128;

  constexpr int KSTEP = (NP == 2) ? 32 : 64;
  const int nt = K / KSTEP;

  auto stage = [&](int t, int i) {
    const int g0 = i * 512 + wave * 64;
    const int ga = g0 + lane;
    const bool isB = ga >= 1024;
    const int gl = ga & 1023;
    const int pl = gl >> 9;
    const int gp = gl & 511;
    const int r = gp >> 2;
    const int cg = (gp & 3) ^ ((r >> 1) & 3);
    const long sP = (NP == 2) ? (isB ? sBp : sAp) : 0;
    const int kOff = (NP == 2) ? 0 : pl * 32;
    const f16* gs = (isB ? Bp : Ap) + (size_t)pl * sP +
                    (size_t)((isB ? bn : bm) + r) * K + t * KSTEP + kOff +
                    cg * 8;
    gl_lds16(gs, &lds[((size_t)(t % 3) * 2048 + g0) * 8]);
  };

  int aoff[2][2], boff[2][4];
#pragma unroll
  for (int pl = 0; pl < 2; ++pl) {
#pragma unroll
    for (int m = 0; m < 2; ++m) {
      const int row = wr + m * 16 + (lane & 15);
      const int kg = (lane >> 4) ^ ((row >> 1) & 3);
      aoff[pl][m] = (pl * 512 + row * 4 + kg) * 8;
    }
#pragma unroll
    for (int n = 0; n < 4; ++n) {
      const int col = wc + n * 16 + (lane & 15);
      const int kg = (lane >> 4) ^ ((col >> 1) & 3);
      boff[pl][n] = (1024 + pl * 512 + col * 4 + kg) * 8;
    }
  }

  f32x4 acc[2][4];
#pragma unroll
  for (int m = 0; m < 2; ++m)
#pragma unroll
    for (int n = 0; n < 4; ++n) acc[m][n] = (f32x4){0.f, 0.f, 0.f, 0.f};

#pragma unroll
  for (int i = 0; i < 4; ++i) stage(0, i);
#pragma unroll
  for (int i = 0; i < 4; ++i) stage(1, i);

  for (int t = 0; t < nt; ++t) {
    const f16* buf = &lds[(size_t)(t % 3) * 2048 * 8];
    if (t + 1 < nt)
      asm volatile("s_waitcnt vmcnt(4)" ::: "memory");
    else
      asm volatile("s_waitcnt vmcnt(0)" ::: "memory");
    asm volatile("s_barrier" ::: "memory");

    half8 af[2][2], b0[2][2];
#pragma unroll
    for (int pl = 0; pl < 2; ++pl) {
#pragma unroll
      for (int m = 0; m < 2; ++m) af[pl][m] = *(const half8*)&buf[aoff[pl][m]];
#pragma unroll
      for (int j = 0; j < 2; ++j) b0[pl][j] = *(const half8*)&buf[boff[pl][j]];
    }
    if (t + 2 < nt) {
      stage(t + 2, 0);
      stage(t + 2, 1);
    }
    __builtin_amdgcn_sched_barrier(0);
    asm volatile("s_barrier" ::: "memory");
    asm volatile("s_waitcnt lgkmcnt(0)" ::: "memory");
    __builtin_amdgcn_sched_barrier(0);
    __builtin_amdgcn_s_setprio(1);
#pragma unroll
    for (int m = 0; m < 2; ++m) {
#pragma unroll
      for (int j = 0; j < 2; ++j) {
        acc[m][j] = __builtin_amdgcn_mfma_f32_16x16x32_f16(af[0][m], b0[0][j],
                                                           acc[m][j], 0, 0, 0);
        if (NP == 2) {
          acc[m][j] = __builtin_amdgcn_mfma_f32_16x16x32_f16(
              af[0][m], b0[1][j], acc[m][j], 0, 0, 0);
          acc[m][j] = __builtin_amdgcn_mfma_f32_16x16x32_f16(
              af[1][m], b0[0][j], acc[m][j], 0, 0, 0);
        } else {
          acc[m][j] = __builtin_amdgcn_mfma_f32_16x16x32_f16(
              af[1][m], b0[1][j], acc[m][j], 0, 0, 0);
        }
      }
    }
    __builtin_amdgcn_s_setprio(0);
    __builtin_amdgcn_sched_barrier(0);
    asm volatile("s_barrier" ::: "memory");

    half8 b1[2][2];
#pragma unroll
    for (int pl = 0; pl < 2; ++pl)
#pragma unroll
      for (int j = 0; j < 2; ++j)
        b1[pl][j] = *(const half8*)&buf[boff[pl][2 + j]];
    if (t + 2 < nt) {
      stage(t + 2, 2);
      stage(t + 2, 3);
    }
    __builtin_amdgcn_sched_barrier(0);
    asm volatile("s_barrier" ::: "memory");
    asm volatile("s_waitcnt lgkmcnt(0)" ::: "memory");
    __builtin_amdgcn_sched_barrier(0);
    __builtin_amdgcn_s_setprio(1);
#pragma unroll
    for (int m = 0; m < 2; ++m) {
#pragma unroll
      for (int j = 0; j < 2; ++j) {
        acc[m][2 + j] = __builtin_amdgcn_mfma_f32_16x16x32_f16(
            af[0][m], b1[0][j], acc[m][2 + j], 0, 0, 0);
        if (NP == 2) {
          acc[m][2 + j] = __builtin_amdgcn_mfma_f32_16x16x32_f16(
              af[0][m], b1[1][j], acc[m][2 + j], 0, 0, 0);
          acc[m][2 + j] = __builtin_amdgcn_mfma_f32_16x16x32_f16(
              af[1][m], b1[0][j], acc[m][2 + j], 0, 0, 0);
        } else {
          acc[m][2 + j] = __builtin_amdgcn_mfma_f32_16x16x32_f16(
              af[1][m], b1[1][j], acc[m][2 + j], 0, 0, 0);
        }
      }
    }
    __builtin_amdgcn_s_setprio(0);
    __builtin_amdgcn_sched_barrier(0);
  }

#pragma unroll
  for (int m = 0; m < 2; ++m) {
#pragma unroll
    for (int n = 0; n < 4; ++n) {
      const int col = bn + wc + n * 16 + (lane & 15);
      const float bv = BIASF ? bias[col] : 0.f;
#pragma unroll
      for (int q = 0; q < 4; ++q) {
        const int row = bm + wr + m * 16 + (lane >> 4) * 4 + q;
        float v = acc[m][n][q] * scale;
        if (EPI == 0) {
          ((float*)Cv)[(size_t)row * N + col] = v + bv;
        } else if (EPI == 1) {
          f16* C = (f16*)Cv;
          const f16 h = (f16)v;
          C[(size_t)row * N + col] = h;
          C[sCp + (size_t)row * N + col] = (f16)(v - (float)h);
        } else {
          ((f16*)Cv)[(size_t)row * N + col] = (f16)v;
        }
      }
    }
  }
}

// ---------------------------------------------------------------------------
// Round-3 2-barrier kernel, kept for the tiny G1 (grid 128)
// ---------------------------------------------------------------------------
template <int NP, int TN, int EPI, bool BIASF, int MINW>
__global__ __launch_bounds__(256, MINW) void gemm_mp(
    const f16* __restrict__ Ap, const f16* __restrict__ Bp,
    void* __restrict__ Cv, const float* __restrict__ bias, int M, int N, int K,
    long sAp, long sBp, long sCp, float scale) {
  constexpr int FR = (TN == 128) ? 4 : 2;
  constexpr int FC = 4;
  constexpr int AG = NP * 512;
  constexpr int BPG = TN * 4;
  __shared__ f16 As[NP * 128 * 32];
  __shared__ f16 Bs[NP * TN * 32];
  const int tid = threadIdx.x;
  const int lane = tid & 63;
  const int wave = tid >> 6;
  const int wr = (TN == 128) ? (wave >> 1) * 64 : wave * 32;
  const int wc = (TN == 128) ? (wave & 1) * 64 : 0;

  const int nwg = gridDim.x * gridDim.y;
  int bid = blockIdx.y * gridDim.x + blockIdx.x;
  bid = (bid & 7) * (nwg >> 3) + (bid >> 3);
  const int bm = (bid / gridDim.x) * 128;
  const int bn = (bid % gridDim.x) * TN;

  int aoff[NP][FR], boff[NP][FC];
#pragma unroll
  for (int p = 0; p < NP; ++p) {
#pragma unroll
    for (int m = 0; m < FR; ++m) {
      const int row = wr + m * 16 + (lane & 15);
      const int kga = (lane >> 4) ^ ((row >> 1) & 3);
      aoff[p][m] = (p * 512 + row * 4 + kga) * 8;
    }
#pragma unroll
    for (int n = 0; n < FC; ++n) {
      const int col = wc + n * 16 + (lane & 15);
      const int kgb = (lane >> 4) ^ ((col >> 1) & 3);
      boff[p][n] = (p * BPG + col * 4 + kgb) * 8;
    }
  }

  f32x4 acc[FR][FC];
#pragma unroll
  for (int m = 0; m < FR; ++m)
#pragma unroll
    for (int n = 0; n < FC; ++n) acc[m][n] = (f32x4){0.f, 0.f, 0.f, 0.f};

  for (int k0 = 0; k0 < K; k0 += 32) {
#pragma unroll
    for (int i = 0; i < (NP * (512 + TN * 4)) / 256; ++i) {
      const int g0 = i * 256 + wave * 64;
      const bool isB = g0 >= AG;
      const int ga0 = g0 - (isB ? AG : 0);
      const int ga = ga0 + lane;
      const int pl = isB ? (ga / BPG) : (ga >> 9);
      const int gp = isB ? (ga % BPG) : (ga & 511);
      const int r = gp >> 2;
      const int cg = (gp & 3) ^ ((r >> 1) & 3);
      const f16* gs = (isB ? Bp + (size_t)pl * sBp + (size_t)(bn + r) * K
                           : Ap + (size_t)pl * sAp + (size_t)(bm + r) * K) +
                      k0 + cg * 8;
      f16* ld = (isB ? Bs : As) + (size_t)ga0 * 8;
      gl_lds16(gs, ld);
    }
    __syncthreads();

    half8 af[NP][FR], bf[NP][FC];
#pragma unroll
    for (int p = 0; p < NP; ++p) {
#pragma unroll
      for (int m = 0; m < FR; ++m) af[p][m] = *(const half8*)&As[aoff[p][m]];
#pragma unroll
      for (int n = 0; n < FC; ++n) bf[p][n] = *(const half8*)&Bs[boff[p][n]];
    }
#pragma unroll
    for (int m = 0; m < FR; ++m) {
#pragma unroll
      for (int n = 0; n < FC; ++n) {
        acc[m][n] = __builtin_amdgcn_mfma_f32_16x16x32_f16(af[0][m], bf[0][n],
                                                           acc[m][n], 0, 0, 0);
        if (NP == 2) {
          acc[m][n] = __builtin_amdgcn_mfma_f32_16x16x32_f16(
              af[0][m], bf[1][n], acc[m][n], 0, 0, 0);
          acc[m][n] = __builtin_amdgcn_mfma_f32_16x16x32_f16(
              af[1][m], bf[0][n], acc[m][n], 0, 0, 0);
        }
      }
    }
    __syncthreads();
  }

#pragma unroll
  for (int m = 0; m < FR; ++m) {
#pragma unroll
    for (int n = 0; n < FC; ++n) {
      const int col = bn + wc + n * 16 + (lane & 15);
      const float bv = BIASF ? bias[col] : 0.f;
#pragma unroll
      for (int q = 0; q < 4; ++q) {
        const int row = bm + wr + m * 16 + (lane >> 4) * 4 + q;
        float v = acc[m][n][q] * scale;
        if (EPI == 0) {
          ((float*)Cv)[(size_t)row * N + col] = v + bv;
        } else if (EPI == 1) {
          f16* C = (f16*)Cv;
          const f16 h = (f16)v;
          C[(size_t)row * N + col] = h;
          C[sCp + (size_t)row * N + col] = (f16)(v - (float)h);
        } else {
          ((f16*)Cv)[(size_t)row * N + col] = (f16)v;
        }
      }
    }
  }
}

// fp32 -> NP fp16 planes (elementwise)
template <int NP>
__global__ __launch_bounds__(256) void split_n(const float* __restrict__ in,
                                               f16* __restrict__ out,
                                               long planeStride, int n4) {
  const int i = blockIdx.x * 256 + threadIdx.x;
  if (i >= n4) return;
  const float4 v = ((const float4*)in)[i];
  const float vv[4] = {v.x, v.y, v.z, v.w};
  half4 h, mm;
#pragma unroll
  for (int q = 0; q < 4; ++q) {
    h[q] = (f16)vv[q];
    if (NP == 2) mm[q] = (f16)(vv[q] - (float)h[q]);
  }
  ((half4*)out)[i] = h;
  if (NP == 2) ((half4*)(out + planeStride))[i] = mm;
}

// fp32 [Mr,Nc] -> NP fp16 planes of the TRANSPOSE [Nc,Mr]
template <int NP>
__global__ __launch_bounds__(256) void split_t(const float* __restrict__ in,
                                               f16* __restrict__ out, int Mr,
                                               int Nc, long planeStride) {
  __shared__ float Ls[64][65];
  const int i0 = blockIdx.y * 64;
  const int j0 = blockIdx.x * 64;
  const int t = threadIdx.x;
  const int r = t >> 4;
  const int c = (t & 15) * 4;
#pragma unroll
  for (int i = 0; i < 4; ++i) {
    const float4 v =
        *(const float4*)&in[(size_t)(i0 + r + i * 16) * Nc + j0 + c];
    Ls[r + i * 16][c + 0] = v.x;
    Ls[r + i * 16][c + 1] = v.y;
    Ls[r + i * 16][c + 2] = v.z;
    Ls[r + i * 16][c + 3] = v.w;
  }
  __syncthreads();
#pragma unroll
  for (int i = 0; i < 4; ++i) {
    const int r2 = r + i * 16;
    half4 h, mm;
#pragma unroll
    for (int q = 0; q < 4; ++q) {
      const float v = Ls[c + q][r2];
      h[q] = (f16)v;
      if (NP == 2) mm[q] = (f16)(v - (float)h[q]);
    }
    *(half4*)&out[(size_t)(j0 + r2) * Mr + i0 + c] = h;
    if (NP == 2)
      *(half4*)&out[planeStride + (size_t)(j0 + r2) * Mr + i0 + c] = mm;
  }
}

// full-row softmax fp32 [4096] -> f16 P row; one block per row.
// Row staged in LDS: 1 HBM read + 1 HBM write instead of 3 reads.
__global__ __launch_bounds__(256) void softmax_p16(const float* __restrict__ L,
                                                   f16* __restrict__ P) {
  __shared__ float row[4096];
  __shared__ float red[8];
  const int rix = blockIdx.x;
  const float* p = L + (size_t)rix * 4096;
  f16* o = P + (size_t)rix * 4096;
  const int tid = threadIdx.x;

  // pass 1: load row -> LDS, running max
  float m = -INFINITY;
  for (int i = tid * 4; i < 4096; i += 1024) {
    const float4 v = *reinterpret_cast<const float4*>(&p[i]);
    *reinterpret_cast<float4*>(&row[i]) = v;
    m = fmaxf(fmaxf(fmaxf(v.x, v.y), fmaxf(v.z, v.w)), m);
  }
#pragma unroll
  for (int off = 32; off > 0; off >>= 1) m = fmaxf(m, __shfl_xor(m, off));
  if ((tid & 63) == 0) red[tid >> 6] = m;
  __syncthreads();
  m = fmaxf(fmaxf(red[0], red[1]), fmaxf(red[2], red[3]));

  // pass 2: exp in LDS, running sum
  float s = 0.f;
  for (int i = tid * 4; i < 4096; i += 1024) {
    float4 v = *reinterpret_cast<const float4*>(&row[i]);
    v.x = expf(v.x - m);
    v.y = expf(v.y - m);
    v.z = expf(v.z - m);
    v.w = expf(v.w - m);
    s += v.x + v.y + v.z + v.w;
    *reinterpret_cast<float4*>(&row[i]) = v;
  }
#pragma unroll
  for (int off = 32; off > 0; off >>= 1) s += __shfl_xor(s, off);
  if ((tid & 63) == 0) red[4 + (tid >> 6)] = s;
  __syncthreads();
  s = red[4] + red[5] + red[6] + red[7];
  const float inv = 1.0f / s;

  // pass 3: normalize + cvt f16 + store
  for (int i = tid * 4; i < 4096; i += 1024) {
    const float4 v = *reinterpret_cast<const float4*>(&row[i]);
    half4 h;
    h[0] = (f16)(v.x * inv);
    h[1] = (f16)(v.y * inv);
    h[2] = (f16)(v.z * inv);
    h[3] = (f16)(v.w * inv);
    *(half4*)&o[i] = h;
  }
}

extern "C" void kernel_launch(void* const* d_in, const int* in_sizes, int n_in,
                              void* d_out, int out_size, void* d_ws,
                              size_t ws_size, hipStream_t stream) {
  const float* X = (const float*)d_in[0];   // [4096,1024]
  const float* R = (const float*)d_in[1];   // [1024,1024]
  const float* Wl = (const float*)d_in[2];  // [1024,1024] (out,in)
  const float* bias = (const float*)d_in[3];
  float* out = (float*)d_out;

  const int Bq = 4096, D = 1024;
  const size_t MiB = 1 << 20;
  uint8_t* w8 = (uint8_t*)d_ws;
  f16* Xp = (f16*)(w8);              // [0,16)  2 planes [4096,1024]
  f16* Tp = (f16*)(w8 + 16 * MiB);   // [16,32) 2 planes [4096,1024]
  f16* Pp = (f16*)(w8);              // [0,32)  1 plane  [4096,4096] (post-SM)
  f16* Wp = (f16*)(w8 + 32 * MiB);   // [32,34) 1 plane  [1024,1024]
  f16* Rp = (f16*)(w8 + 36 * MiB);   // [36,40) 2 planes
  f16* Rtp = (f16*)(w8 + 40 * MiB);  // [40,44) 2 planes
  f16* Mtp = (f16*)(w8 + 44 * MiB);  // [44,48) 2 planes
  float* L = (float*)(w8 + 36 * MiB);  // [36,100) fp32 [4096,4096]
  f16* Xh = (f16*)(w8 + 36 * MiB);   // [36,44) 1 plane [4096,1024] (post-SM)
  f16* Yt = (f16*)(w8 + 44 * MiB);   // [44,52) 1 plane [1024,4096] (post-SM)

  const long sR = (long)D * D, sX = (long)Bq * D;
  const dim3 blk(256), blk512(512);

  split_n<2><<<D * D / 1024, blk, 0, stream>>>(R, Rp, sR, D * D / 4);
  split_t<2><<<dim3(D / 64, D / 64), blk, 0, stream>>>(R, Rtp, D, D, sR);
  split_n<2><<<Bq * D / 1024, blk, 0, stream>>>(X, Xp, sX, Bq * D / 4);
  split_n<1><<<D * D / 1024, blk, 0, stream>>>(Wl, Wp, 0, D * D / 4);

  // G1: Mt = Rt . R^T  (split2 out), grid 128
  gemm_mp<2, 64, 1, false, 2><<<dim3(D / 64, D / 128), blk, 0, stream>>>(
      Rtp, Rp, Mtp, nullptr, D, D, D, sR, sR, sR, 1.f);
  // G2: T = Xp . Mt^T  (split2 out), dp, grid 256
  gemm_dp<2, 1, false><<<dim3(D / 128, Bq / 128), blk512, 0, stream>>>(
      Xp, Mtp, Tp, nullptr, Bq, D, D, sX, sR, sX, 1.f);
  // G4: L = scale * Tp . Xp^T  (fp32), 256^2 barrier-free, grid 16x16=256
  gemm_q2<<<dim3(Bq / 256, Bq / 256), blk512, 0, stream>>>(
      Tp, Xp, L, Bq, D, sX, sX, 0.03125f);
  // softmax rows -> f16 P (overwrites Xp/Tp)
  softmax_p16<<<dim3(Bq), blk, 0, stream>>>(L, Pp);
  // re-split X (L region dead now)
  split_n<1><<<Bq * D / 1024, blk, 0, stream>>>(X, Xh, 0, Bq * D / 4);
  // G3: Yt = Wp . Xh^T = (X W^T)^T  (f16), dp, grid 256
  gemm_dp<1, 2, false><<<dim3(Bq / 128, D / 128), blk512, 0, stream>>>(
      Wp, Xh, Yt, nullptr, D, Bq, D, 0, 0, 0, 1.f);
  // G5: out = Pp . Yt^T + bias  (fp32), dp, grid 256
  gemm_dp<1, 0, true><<<dim3(D / 128, Bq / 128), blk512, 0, stream>>>(
      Pp, Yt, out, bias, Bq, D, Bq, 0, 0, 0, 1.f);
}

// Round 7
// 241.201 us; speedup vs baseline: 5.3202x; 1.0204x over previous
//
#include <hip/hip_runtime.h>
#include <math.h>
#include <stdint.h>

using f16 = _Float16;
using half8 = __attribute__((ext_vector_type(8))) f16;
using half4 = __attribute__((ext_vector_type(4))) f16;
using f32x4 = __attribute__((ext_vector_type(4))) float;

__device__ __forceinline__ void gl_lds16(const f16* g, f16* l) {
  __builtin_amdgcn_global_load_lds(
      (const __attribute__((address_space(1))) void*)g,
      (__attribute__((address_space(3))) void*)l, 16, 0, 0);
}

// ---------------------------------------------------------------------------
// 256^2-tile Markidis GEMM, single-barrier + counted-vmcnt (T2+T4+T5):
// Lsplit[M,N] = scale * (A.B^T hh+hm+mh over split2 planes), split2-f16 out.
// 8 waves (wave tile 128x64), KSTEP=32, double-buffered 128KB LDS.
// Per tile: s_barrier; issue next-tile half-stage; s_waitcnt vmcnt(4);
// then 4 MFMA quadrants with ds_reads pipelined one quadrant ahead.
// Safety: the barrier proves every wave consumed its reads of the buffer the
// new stage-writes land in (their Q4 MFMAs lgkm-waited before the barrier).
// ---------------------------------------------------------------------------
__global__ __launch_bounds__(512, 2) void gemm_q3(
    const f16* __restrict__ Ap, const f16* __restrict__ Bp,
    f16* __restrict__ Ch, long sCp, int N, int K, long sAp, long sBp,
    float scale) {
  // buffer (granules of 16B): [A: pl*1024 + r*4 + kg | B: 2048 + same]
  __shared__ f16 lds[2 * 4096 * 8];
  const int tid = threadIdx.x;
  const int lane = tid & 63;
  const int wave = tid >> 6;
  const int wr = (wave >> 2) * 128;
  const int wc = (wave & 3) * 64;

  const int nwg = gridDim.x * gridDim.y;
  int bid = blockIdx.y * gridDim.x + blockIdx.x;
  bid = (bid & 7) * (nwg >> 3) + (bid >> 3);  // XCD-aware (nwg % 8 == 0)
  const int bm = (bid / gridDim.x) * 256;
  const int bn = (bid % gridDim.x) * 256;

  const int nt = K / 32;

  // stage part i (0..7) of tile t: 512 granules, 1 gl_lds/thread.
  auto stage = [&](int t, int i) {
    const int g0 = i * 512 + wave * 64;  // wave-uniform granule base
    const int ga = g0 + lane;
    const bool isB = ga >= 2048;
    const int gl = ga & 2047;
    const int pl = gl >> 10;
    const int gp = gl & 1023;
    const int r = gp >> 2;
    const int cg = (gp & 3) ^ ((r >> 1) & 3);  // XOR-swizzled source granule
    const f16* gs = (isB ? Bp + (size_t)pl * sBp + (size_t)(bn + r) * K
                         : Ap + (size_t)pl * sAp + (size_t)(bm + r) * K) +
                    t * 32 + cg * 8;
    gl_lds16(gs, &lds[((size_t)(t & 1) * 4096 + g0) * 8]);
  };

  // fragment ds_read offsets (halfs within buffer), swizzled
  int aoff[2][8], boff[2][4];
#pragma unroll
  for (int pl = 0; pl < 2; ++pl) {
#pragma unroll
    for (int fr = 0; fr < 8; ++fr) {
      const int row = wr + fr * 16 + (lane & 15);
      const int kg = (lane >> 4) ^ ((row >> 1) & 3);
      aoff[pl][fr] = (pl * 1024 + row * 4 + kg) * 8;
    }
#pragma unroll
    for (int fc = 0; fc < 4; ++fc) {
      const int col = wc + fc * 16 + (lane & 15);
      const int kg = (lane >> 4) ^ ((col >> 1) & 3);
      boff[pl][fc] = (2048 + pl * 1024 + col * 4 + kg) * 8;
    }
  }

  f32x4 acc[8][4];
#pragma unroll
  for (int m = 0; m < 8; ++m)
#pragma unroll
    for (int n = 0; n < 4; ++n) acc[m][n] = (f32x4){0.f, 0.f, 0.f, 0.f};

  half8 af0[2][4], af1[2][4], bf0[2][2], bf1[2][2];

#define LOAD_A(dst, h)                                          \
  _Pragma("unroll") for (int pl = 0; pl < 2; ++pl)              \
      _Pragma("unroll") for (int i = 0; i < 4; ++i) dst[pl][i] = \
          *(const half8*)&buf[aoff[pl][(h) * 4 + i]];
#define LOAD_B(dst, h)                                          \
  _Pragma("unroll") for (int pl = 0; pl < 2; ++pl)              \
      _Pragma("unroll") for (int j = 0; j < 2; ++j) dst[pl][j] = \
          *(const half8*)&buf[boff[pl][(h) * 2 + j]];
#define MFMA_Q(A, B, ah, bh)                                                  \
  _Pragma("unroll") for (int i = 0; i < 4; ++i)                               \
      _Pragma("unroll") for (int j = 0; j < 2; ++j) {                         \
    f32x4& c = acc[(ah) * 4 + i][(bh) * 2 + j];                               \
    c = __builtin_amdgcn_mfma_f32_16x16x32_f16(A[0][i], B[0][j], c, 0, 0, 0); \
    c = __builtin_amdgcn_mfma_f32_16x16x32_f16(A[0][i], B[1][j], c, 0, 0, 0); \
    c = __builtin_amdgcn_mfma_f32_16x16x32_f16(A[1][i], B[0][j], c, 0, 0, 0); \
  }
#define SBAR0() __builtin_amdgcn_sched_barrier(0)

  // prologue: prime tile 0
#pragma unroll
  for (int i = 0; i < 8; ++i) stage(0, i);

  for (int t = 0; t < nt; ++t) {
    const f16* buf = &lds[(size_t)(t & 1) * 4096 * 8];
    asm volatile("s_barrier" ::: "memory");
    const bool pf = (t + 1 < nt);
    if (pf) {
      stage(t + 1, 0); stage(t + 1, 1); stage(t + 1, 2); stage(t + 1, 3);
      SBAR0();
      asm volatile("s_waitcnt vmcnt(4)" ::: "memory");  // tile t landed
    } else {
      asm volatile("s_waitcnt vmcnt(0)" ::: "memory");
    }
    SBAR0();
    LOAD_A(af0, 0);
    LOAD_B(bf0, 0);
    LOAD_B(bf1, 1);  // Q2 frags prefetched
    SBAR0();
    __builtin_amdgcn_s_setprio(1);
    MFMA_Q(af0, bf0, 0, 0);
    __builtin_amdgcn_s_setprio(0);
    SBAR0();
    LOAD_A(af1, 1);  // Q3/Q4 A-frags
    if (pf) { stage(t + 1, 4); stage(t + 1, 5); stage(t + 1, 6); stage(t + 1, 7); }
    SBAR0();
    __builtin_amdgcn_s_setprio(1);
    MFMA_Q(af0, bf1, 0, 1);
    __builtin_amdgcn_s_setprio(0);
    SBAR0();
    LOAD_B(bf0, 0);  // re-read B0 for Q4
    SBAR0();
    __builtin_amdgcn_s_setprio(1);
    MFMA_Q(af1, bf1, 1, 1);
    __builtin_amdgcn_s_setprio(0);
    SBAR0();
    __builtin_amdgcn_s_setprio(1);
    MFMA_Q(af1, bf0, 1, 0);
    __builtin_amdgcn_s_setprio(0);
    SBAR0();
  }
#undef LOAD_A
#undef LOAD_B
#undef MFMA_Q
#undef SBAR0

  // epilogue: split2-f16 planes. C/D layout: col = lane&15, row = (lane>>4)*4+q
#pragma unroll
  for (int m = 0; m < 8; ++m) {
#pragma unroll
    for (int n = 0; n < 4; ++n) {
      const int col = bn + wc + n * 16 + (lane & 15);
#pragma unroll
      for (int q = 0; q < 4; ++q) {
        const int row = bm + wr + m * 16 + (lane >> 4) * 4 + q;
        const float v = acc[m][n][q] * scale;
        const f16 h = (f16)v;
        Ch[(size_t)row * N + col] = h;
        Ch[sCp + (size_t)row * N + col] = (f16)(v - (float)h);
      }
    }
  }
}

// ---------------------------------------------------------------------------
// 128^2 deep-pipelined GEMM (round 4), used for G2/G3/G5.
// ---------------------------------------------------------------------------
template <int NP, int EPI, bool BIASF>
__global__ __launch_bounds__(512, 2) void gemm_dp(
    const f16* __restrict__ Ap, const f16* __restrict__ Bp,
    void* __restrict__ Cv, const float* __restrict__ bias, int M, int N, int K,
    long sAp, long sBp, long sCp, float scale) {
  __shared__ f16 lds[3 * 2048 * 8];
  const int tid = threadIdx.x;
  const int lane = tid & 63;
  const int wave = tid >> 6;
  const int wr = (wave >> 1) * 32;
  const int wc = (wave & 1) * 64;

  const int nwg = gridDim.x * gridDim.y;
  int bid = blockIdx.y * gridDim.x + blockIdx.x;
  bid = (bid & 7) * (nwg >> 3) + (bid >> 3);
  const int bm = (bid / gridDim.x) * 128;
  const int bn = (bid % gridDim.x) * 128;

  constexpr int KSTEP = (NP == 2) ? 32 : 64;
  const int nt = K / KSTEP;

  auto stage = [&](int t, int i) {
    const int g0 = i * 512 + wave * 64;
    const int ga = g0 + lane;
    const bool isB = ga >= 1024;
    const int gl = ga & 1023;
    const int pl = gl >> 9;
    const int gp = gl & 511;
    const int r = gp >> 2;
    const int cg = (gp & 3) ^ ((r >> 1) & 3);
    const long sP = (NP == 2) ? (isB ? sBp : sAp) : 0;
    const int kOff = (NP == 2) ? 0 : pl * 32;
    const f16* gs = (isB ? Bp : Ap) + (size_t)pl * sP +
                    (size_t)((isB ? bn : bm) + r) * K + t * KSTEP + kOff +
                    cg * 8;
    gl_lds16(gs, &lds[((size_t)(t % 3) * 2048 + g0) * 8]);
  };

  int aoff[2][2], boff[2][4];
#pragma unroll
  for (int pl = 0; pl < 2; ++pl) {
#pragma unroll
    for (int m = 0; m < 2; ++m) {
      const int row = wr + m * 16 + (lane & 15);
      const int kg = (lane >> 4) ^ ((row >> 1) & 3);
      aoff[pl][m] = (pl * 512 + row * 4 + kg) * 8;
    }
#pragma unroll
    for (int n = 0; n < 4; ++n) {
      const int col = wc + n * 16 + (lane & 15);
      const int kg = (lane >> 4) ^ ((col >> 1) & 3);
      boff[pl][n] = (1024 + pl * 512 + col * 4 + kg) * 8;
    }
  }

  f32x4 acc[2][4];
#pragma unroll
  for (int m = 0; m < 2; ++m)
#pragma unroll
    for (int n = 0; n < 4; ++n) acc[m][n] = (f32x4){0.f, 0.f, 0.f, 0.f};

#pragma unroll
  for (int i = 0; i < 4; ++i) stage(0, i);
#pragma unroll
  for (int i = 0; i < 4; ++i) stage(1, i);

  for (int t = 0; t < nt; ++t) {
    const f16* buf = &lds[(size_t)(t % 3) * 2048 * 8];
    if (t + 1 < nt)
      asm volatile("s_waitcnt vmcnt(4)" ::: "memory");
    else
      asm volatile("s_waitcnt vmcnt(0)" ::: "memory");
    asm volatile("s_barrier" ::: "memory");

    half8 af[2][2], b0[2][2];
#pragma unroll
    for (int pl = 0; pl < 2; ++pl) {
#pragma unroll
      for (int m = 0; m < 2; ++m) af[pl][m] = *(const half8*)&buf[aoff[pl][m]];
#pragma unroll
      for (int j = 0; j < 2; ++j) b0[pl][j] = *(const half8*)&buf[boff[pl][j]];
    }
    if (t + 2 < nt) {
      stage(t + 2, 0);
      stage(t + 2, 1);
    }
    __builtin_amdgcn_sched_barrier(0);
    asm volatile("s_barrier" ::: "memory");
    asm volatile("s_waitcnt lgkmcnt(0)" ::: "memory");
    __builtin_amdgcn_sched_barrier(0);
    __builtin_amdgcn_s_setprio(1);
#pragma unroll
    for (int m = 0; m < 2; ++m) {
#pragma unroll
      for (int j = 0; j < 2; ++j) {
        acc[m][j] = __builtin_amdgcn_mfma_f32_16x16x32_f16(af[0][m], b0[0][j],
                                                           acc[m][j], 0, 0, 0);
        if (NP == 2) {
          acc[m][j] = __builtin_amdgcn_mfma_f32_16x16x32_f16(
              af[0][m], b0[1][j], acc[m][j], 0, 0, 0);
          acc[m][j] = __builtin_amdgcn_mfma_f32_16x16x32_f16(
              af[1][m], b0[0][j], acc[m][j], 0, 0, 0);
        } else {
          acc[m][j] = __builtin_amdgcn_mfma_f32_16x16x32_f16(
              af[1][m], b0[1][j], acc[m][j], 0, 0, 0);
        }
      }
    }
    __builtin_amdgcn_s_setprio(0);
    __builtin_amdgcn_sched_barrier(0);
    asm volatile("s_barrier" ::: "memory");

    half8 b1[2][2];
#pragma unroll
    for (int pl = 0; pl < 2; ++pl)
#pragma unroll
      for (int j = 0; j < 2; ++j)
        b1[pl][j] = *(const half8*)&buf[boff[pl][2 + j]];
    if (t + 2 < nt) {
      stage(t + 2, 2);
      stage(t + 2, 3);
    }
    __builtin_amdgcn_sched_barrier(0);
    asm volatile("s_barrier" ::: "memory");
    asm volatile("s_waitcnt lgkmcnt(0)" ::: "memory");
    __builtin_amdgcn_sched_barrier(0);
    __builtin_amdgcn_s_setprio(1);
#pragma unroll
    for (int m = 0; m < 2; ++m) {
#pragma unroll
      for (int j = 0; j < 2; ++j) {
        acc[m][2 + j] = __builtin_amdgcn_mfma_f32_16x16x32_f16(
            af[0][m], b1[0][j], acc[m][2 + j], 0, 0, 0);
        if (NP == 2) {
          acc[m][2 + j] = __builtin_amdgcn_mfma_f32_16x16x32_f16(
              af[0][m], b1[1][j], acc[m][2 + j], 0, 0, 0);
          acc[m][2 + j] = __builtin_amdgcn_mfma_f32_16x16x32_f16(
              af[1][m], b1[0][j], acc[m][2 + j], 0, 0, 0);
        } else {
          acc[m][2 + j] = __builtin_amdgcn_mfma_f32_16x16x32_f16(
              af[1][m], b1[1][j], acc[m][2 + j], 0, 0, 0);
        }
      }
    }
    __builtin_amdgcn_s_setprio(0);
    __builtin_amdgcn_sched_barrier(0);
  }

#pragma unroll
  for (int m = 0; m < 2; ++m) {
#pragma unroll
    for (int n = 0; n < 4; ++n) {
      const int col = bn + wc + n * 16 + (lane & 15);
      const float bv = BIASF ? bias[col] : 0.f;
#pragma unroll
      for (int q = 0; q < 4; ++q) {
        const int row = bm + wr + m * 16 + (lane >> 4) * 4 + q;
        float v = acc[m][n][q] * scale;
        if (EPI == 0) {
          ((float*)Cv)[(size_t)row * N + col] = v + bv;
        } else if (EPI == 1) {
          f16* C = (f16*)Cv;
          const f16 h = (f16)v;
          C[(size_t)row * N + col] = h;
          C[sCp + (size_t)row * N + col] = (f16)(v - (float)h);
        } else {
          ((f16*)Cv)[(size_t)row * N + col] = (f16)v;
        }
      }
    }
  }
}

// ---------------------------------------------------------------------------
// Round-3 2-barrier kernel, kept for the tiny G1 (grid 128)
// ---------------------------------------------------------------------------
template <int NP, int TN, int EPI, bool BIASF, int MINW>
__global__ __launch_bounds__(256, MINW) void gemm_mp(
    const f16* __restrict__ Ap, const f16* __restrict__ Bp,
    void* __restrict__ Cv, const float* __restrict__ bias, int M, int N, int K,
    long sAp, long sBp, long sCp, float scale) {
  constexpr int FR = (TN == 128) ? 4 : 2;
  constexpr int FC = 4;
  constexpr int AG = NP * 512;
  constexpr int BPG = TN * 4;
  __shared__ f16 As[NP * 128 * 32];
  __shared__ f16 Bs[NP * TN * 32];
  const int tid = threadIdx.x;
  const int lane = tid & 63;
  const int wave = tid >> 6;
  const int wr = (TN == 128) ? (wave >> 1) * 64 : wave * 32;
  const int wc = (TN == 128) ? (wave & 1) * 64 : 0;

  const int nwg = gridDim.x * gridDim.y;
  int bid = blockIdx.y * gridDim.x + blockIdx.x;
  bid = (bid & 7) * (nwg >> 3) + (bid >> 3);
  const int bm = (bid / gridDim.x) * 128;
  const int bn = (bid % gridDim.x) * TN;

  int aoff[NP][FR], boff[NP][FC];
#pragma unroll
  for (int p = 0; p < NP; ++p) {
#pragma unroll
    for (int m = 0; m < FR; ++m) {
      const int row = wr + m * 16 + (lane & 15);
      const int kga = (lane >> 4) ^ ((row >> 1) & 3);
      aoff[p][m] = (p * 512 + row * 4 + kga) * 8;
    }
#pragma unroll
    for (int n = 0; n < FC; ++n) {
      const int col = wc + n * 16 + (lane & 15);
      const int kgb = (lane >> 4) ^ ((col >> 1) & 3);
      boff[p][n] = (p * BPG + col * 4 + kgb) * 8;
    }
  }

  f32x4 acc[FR][FC];
#pragma unroll
  for (int m = 0; m < FR; ++m)
#pragma unroll
    for (int n = 0; n < FC; ++n) acc[m][n] = (f32x4){0.f, 0.f, 0.f, 0.f};

  for (int k0 = 0; k0 < K; k0 += 32) {
#pragma unroll
    for (int i = 0; i < (NP * (512 + TN * 4)) / 256; ++i) {
      const int g0 = i * 256 + wave * 64;
      const bool isB = g0 >= AG;
      const int ga0 = g0 - (isB ? AG : 0);
      const int ga = ga0 + lane;
      const int pl = isB ? (ga / BPG) : (ga >> 9);
      const int gp = isB ? (ga % BPG) : (ga & 511);
      const int r = gp >> 2;
      const int cg = (gp & 3) ^ ((r >> 1) & 3);
      const f16* gs = (isB ? Bp + (size_t)pl * sBp + (size_t)(bn + r) * K
                           : Ap + (size_t)pl * sAp + (size_t)(bm + r) * K) +
                      k0 + cg * 8;
      f16* ld = (isB ? Bs : As) + (size_t)ga0 * 8;
      gl_lds16(gs, ld);
    }
    __syncthreads();

    half8 af[NP][FR], bf[NP][FC];
#pragma unroll
    for (int p = 0; p < NP; ++p) {
#pragma unroll
      for (int m = 0; m < FR; ++m) af[p][m] = *(const half8*)&As[aoff[p][m]];
#pragma unroll
      for (int n = 0; n < FC; ++n) bf[p][n] = *(const half8*)&Bs[boff[p][n]];
    }
#pragma unroll
    for (int m = 0; m < FR; ++m) {
#pragma unroll
      for (int n = 0; n < FC; ++n) {
        acc[m][n] = __builtin_amdgcn_mfma_f32_16x16x32_f16(af[0][m], bf[0][n],
                                                           acc[m][n], 0, 0, 0);
        if (NP == 2) {
          acc[m][n] = __builtin_amdgcn_mfma_f32_16x16x32_f16(
              af[0][m], bf[1][n], acc[m][n], 0, 0, 0);
          acc[m][n] = __builtin_amdgcn_mfma_f32_16x16x32_f16(
              af[1][m], bf[0][n], acc[m][n], 0, 0, 0);
        }
      }
    }
    __syncthreads();
  }

#pragma unroll
  for (int m = 0; m < FR; ++m) {
#pragma unroll
    for (int n = 0; n < FC; ++n) {
      const int col = bn + wc + n * 16 + (lane & 15);
      const float bv = BIASF ? bias[col] : 0.f;
#pragma unroll
      for (int q = 0; q < 4; ++q) {
        const int row = bm + wr + m * 16 + (lane >> 4) * 4 + q;
        float v = acc[m][n][q] * scale;
        if (EPI == 0) {
          ((float*)Cv)[(size_t)row * N + col] = v + bv;
        } else if (EPI == 1) {
          f16* C = (f16*)Cv;
          const f16 h = (f16)v;
          C[(size_t)row * N + col] = h;
          C[sCp + (size_t)row * N + col] = (f16)(v - (float)h);
        } else {
          ((f16*)Cv)[(size_t)row * N + col] = (f16)v;
        }
      }
    }
  }
}

// fp32 -> NP fp16 planes (elementwise)
template <int NP>
__global__ __launch_bounds__(256) void split_n(const float* __restrict__ in,
                                               f16* __restrict__ out,
                                               long planeStride, int n4) {
  const int i = blockIdx.x * 256 + threadIdx.x;
  if (i >= n4) return;
  const float4 v = ((const float4*)in)[i];
  const float vv[4] = {v.x, v.y, v.z, v.w};
  half4 h, mm;
#pragma unroll
  for (int q = 0; q < 4; ++q) {
    h[q] = (f16)vv[q];
    if (NP == 2) mm[q] = (f16)(vv[q] - (float)h[q]);
  }
  ((half4*)out)[i] = h;
  if (NP == 2) ((half4*)(out + planeStride))[i] = mm;
}

// fp32 [Mr,Nc] -> NP fp16 planes of the TRANSPOSE [Nc,Mr]
template <int NP>
__global__ __launch_bounds__(256) void split_t(const float* __restrict__ in,
                                               f16* __restrict__ out, int Mr,
                                               int Nc, long planeStride) {
  __shared__ float Ls[64][65];
  const int i0 = blockIdx.y * 64;
  const int j0 = blockIdx.x * 64;
  const int t = threadIdx.x;
  const int r = t >> 4;
  const int c = (t & 15) * 4;
#pragma unroll
  for (int i = 0; i < 4; ++i) {
    const float4 v =
        *(const float4*)&in[(size_t)(i0 + r + i * 16) * Nc + j0 + c];
    Ls[r + i * 16][c + 0] = v.x;
    Ls[r + i * 16][c + 1] = v.y;
    Ls[r + i * 16][c + 2] = v.z;
    Ls[r + i * 16][c + 3] = v.w;
  }
  __syncthreads();
#pragma unroll
  for (int i = 0; i < 4; ++i) {
    const int r2 = r + i * 16;
    half4 h, mm;
#pragma unroll
    for (int q = 0; q < 4; ++q) {
      const float v = Ls[c + q][r2];
      h[q] = (f16)v;
      if (NP == 2) mm[q] = (f16)(v - (float)h[q]);
    }
    *(half4*)&out[(size_t)(j0 + r2) * Mr + i0 + c] = h;
    if (NP == 2)
      *(half4*)&out[planeStride + (size_t)(j0 + r2) * Mr + i0 + c] = mm;
  }
}

// row softmax over split2-f16 logits [4096] -> f16 P row; one block per row.
__global__ __launch_bounds__(256) void softmax_ps(const f16* __restrict__ Lh,
                                                  long sL,
                                                  f16* __restrict__ P) {
  __shared__ float row[4096];
  __shared__ float red[8];
  const int rix = blockIdx.x;
  const f16* ph = Lh + (size_t)rix * 4096;
  const f16* pm = ph + sL;
  f16* o = P + (size_t)rix * 4096;
  const int tid = threadIdx.x;

  // pass 1: load both planes -> f32 row in LDS, running max
  float mx = -INFINITY;
  for (int i = tid * 8; i < 4096; i += 2048) {
    const half8 h = *(const half8*)&ph[i];
    const half8 mseg = *(const half8*)&pm[i];
#pragma unroll
    for (int q = 0; q < 8; ++q) {
      const float v = (float)h[q] + (float)mseg[q];
      row[i + q] = v;
      mx = fmaxf(mx, v);
    }
  }
#pragma unroll
  for (int off = 32; off > 0; off >>= 1) mx = fmaxf(mx, __shfl_xor(mx, off));
  if ((tid & 63) == 0) red[tid >> 6] = mx;
  __syncthreads();
  mx = fmaxf(fmaxf(red[0], red[1]), fmaxf(red[2], red[3]));

  // pass 2: exp in LDS, running sum
  float s = 0.f;
  for (int i = tid * 4; i < 4096; i += 1024) {
    float4 v = *reinterpret_cast<const float4*>(&row[i]);
    v.x = expf(v.x - mx);
    v.y = expf(v.y - mx);
    v.z = expf(v.z - mx);
    v.w = expf(v.w - mx);
    s += v.x + v.y + v.z + v.w;
    *reinterpret_cast<float4*>(&row[i]) = v;
  }
#pragma unroll
  for (int off = 32; off > 0; off >>= 1) s += __shfl_xor(s, off);
  if ((tid & 63) == 0) red[4 + (tid >> 6)] = s;
  __syncthreads();
  s = red[4] + red[5] + red[6] + red[7];
  const float inv = 1.0f / s;

  // pass 3: normalize + cvt f16 + store
  for (int i = tid * 8; i < 4096; i += 2048) {
    half8 h;
#pragma unroll
    for (int q = 0; q < 8; ++q) h[q] = (f16)(row[i + q] * inv);
    *(half8*)&o[i] = h;
  }
}

extern "C" void kernel_launch(void* const* d_in, const int* in_sizes, int n_in,
                              void* d_out, int out_size, void* d_ws,
                              size_t ws_size, hipStream_t stream) {
  const float* X = (const float*)d_in[0];   // [4096,1024]
  const float* R = (const float*)d_in[1];   // [1024,1024]
  const float* Wl = (const float*)d_in[2];  // [1024,1024] (out,in)
  const float* bias = (const float*)d_in[3];
  float* out = (float*)d_out;

  const int Bq = 4096, D = 1024;
  const size_t MiB = 1 << 20;
  uint8_t* w8 = (uint8_t*)d_ws;
  // Layout (live-range checked):
  //  Xp [0,16) split2 X           (dead after G4; Pp overwrites)
  //  Tp [16,32) split2 T          (dead after G4)
  //  Yt [32,40) f16 (X W^T)^T     (live until G5)
  //  Wp [40,42) f16 W             (dead after G3)
  //  Rp [42,46) Rtp [46,50) Mtp [50,54)  (dead after G2)
  //  Lh [54,70) Lm [70,86) split2 logits (dead after softmax)
  //  Pp [0,32)  f16 P             (written by softmax, read by G5)
  f16* Xp = (f16*)(w8);
  f16* Tp = (f16*)(w8 + 16 * MiB);
  f16* Yt = (f16*)(w8 + 32 * MiB);
  f16* Wp = (f16*)(w8 + 40 * MiB);
  f16* Rp = (f16*)(w8 + 42 * MiB);
  f16* Rtp = (f16*)(w8 + 46 * MiB);
  f16* Mtp = (f16*)(w8 + 50 * MiB);
  f16* Lh = (f16*)(w8 + 54 * MiB);
  f16* Pp = (f16*)(w8);

  const long sR = (long)D * D, sX = (long)Bq * D;
  const long sL = (long)Bq * Bq;  // 16 MiB / 2 B
  const dim3 blk(256), blk512(512);

  split_n<2><<<D * D / 1024, blk, 0, stream>>>(R, Rp, sR, D * D / 4);
  split_t<2><<<dim3(D / 64, D / 64), blk, 0, stream>>>(R, Rtp, D, D, sR);
  split_n<2><<<Bq * D / 1024, blk, 0, stream>>>(X, Xp, sX, Bq * D / 4);
  split_n<1><<<D * D / 1024, blk, 0, stream>>>(Wl, Wp, 0, D * D / 4);

  // G1: Mt = Rt . R^T  (split2 out), grid 128
  gemm_mp<2, 64, 1, false, 2><<<dim3(D / 64, D / 128), blk, 0, stream>>>(
      Rtp, Rp, Mtp, nullptr, D, D, D, sR, sR, sR, 1.f);
  // G3: Yt = Wp . (Xp h-plane)^T = (X W^T)^T  (f16), dp, grid 256
  gemm_dp<1, 2, false><<<dim3(Bq / 128, D / 128), blk512, 0, stream>>>(
      Wp, Xp, Yt, nullptr, D, Bq, D, 0, 0, 0, 1.f);
  // G2: T = Xp . Mt^T  (split2 out), dp, grid 256
  gemm_dp<2, 1, false><<<dim3(D / 128, Bq / 128), blk512, 0, stream>>>(
      Xp, Mtp, Tp, nullptr, Bq, D, D, sX, sR, sX, 1.f);
  // G4: L = scale * Tp . Xp^T  (split2-f16 out), 256^2 counted-vmcnt, grid 256
  gemm_q3<<<dim3(Bq / 256, Bq / 256), blk512, 0, stream>>>(
      Tp, Xp, Lh, sL, Bq, D, sX, sX, 0.03125f);
  // softmax rows (h+m combine) -> f16 P (overwrites Xp/Tp)
  softmax_ps<<<dim3(Bq), blk, 0, stream>>>(Lh, sL, Pp);
  // G5: out = Pp . Yt^T + bias  (fp32), dp, grid 256
  gemm_dp<1, 0, true><<<dim3(D / 128, Bq / 128), blk512, 0, stream>>>(
      Pp, Yt, out, bias, Bq, D, Bq, 0, 0, 0, 1.f);
}